// Round 1
// 219.981 us; speedup vs baseline: 1.0310x; 1.0310x over previous
//
#include <hip/hip_runtime.h>
#include <hip/hip_bf16.h>
#include <math.h>

#define KCOMP 32
#define DDIM  128
#define NPTS  65536
#define GMM_EPS 1e-6f
#define SA 129   // LDS row stride (odd -> conflict-free for scalar col access)
#define UFT 1280 // uint4 per component: 20 nonzero (db,kc) tiles * 64 lanes

typedef __attribute__((ext_vector_type(8)))  __bf16 bf16x8;
typedef __attribute__((ext_vector_type(16))) float  f32x16;

__device__ __forceinline__ unsigned short f2bf(float f){
  unsigned u = __builtin_bit_cast(unsigned, f);
  u = (u + 0x7FFFu + ((u >> 16) & 1u)) >> 16;   // RNE
  return (unsigned short)u;
}
__device__ __forceinline__ float rlane(float v, int lsrc){
  return __builtin_bit_cast(float, __builtin_amdgcn_readlane(__builtin_bit_cast(int, v), lsrc));
}

// ---------------------------------------------------------------------------
// chol_inv32: register-resident Cholesky + triangular inverse of one 32x32
// SPD block (unchanged, validated).
// ---------------------------------------------------------------------------
__device__ __noinline__ float chol_inv32(float* __restrict__ Ab,
                                         float* __restrict__ Wb,
                                         const int c){
  float ar[32], lr[32], rd[32], v[32];
  #pragma unroll
  for(int i=0;i<32;i++) ar[i] = Ab[i*SA + c];
  float hl = 0.f;
  #pragma unroll
  for(int j=0;j<32;j++){
    float d   = rlane(ar[j], j);
    float rsd = rsqrtf(d);
    hl += logf(d);
    rd[j] = rsd;
    float Lcj  = ar[j]*rsd;
    lr[j] = (c>=j) ? Lcj : 0.f;
    float coef = Lcj*rsd;
    #pragma unroll
    for(int i=j;i<32;i++){
      float bij = rlane(ar[i], j);
      ar[i] = fmaf(-bij, coef, ar[i]);
    }
  }
  #pragma unroll
  for(int j=0;j<32;j++) Ab[c*SA + j] = lr[j];
  #pragma unroll
  for(int i=0;i<32;i++){
    float s = (i==c) ? 1.f : 0.f;
    #pragma unroll
    for(int p=0;p<i;p++) s = fmaf(-rlane(lr[p], i), v[p], s);
    v[i] = s * rd[i];
  }
  #pragma unroll
  for(int i=0;i<32;i++) Wb[i*SA + c] = v[i];
  return 0.5f*hl;
}

// ---------------------------------------------------------------------------
// k_prep: one block (256 thr) per component. Blocked Cholesky+inverse
// (unchanged), then NEW tail: m' = U*mu, q = U^T m' (bf16 A-frag panel),
// c3 = log w - hsum - D/2 log2pi - 0.5*||m'||^2, and TIGHT-PACKED lower-
// triangular U frags (20 tiles of (32row x 16kc) instead of 32).
// ---------------------------------------------------------------------------
__global__ __launch_bounds__(256) void k_prep(const float* __restrict__ cov,
                                              const float* __restrict__ wts,
                                              const float* __restrict__ means,
                                              float* __restrict__ ws_c3,
                                              unsigned short* __restrict__ qfrag,
                                              unsigned short* __restrict__ ufrag){
  __shared__ float A[DDIM*SA];      // 64.5 KB: cov -> L (lower)
  __shared__ float W[DDIM*SA];      // 64.5 KB: U = L^{-1} (lower), 0 above
  __shared__ float Tb[3*32*33];     // scratch; later holds m' [0..127], q [128..255]
  __shared__ float muS[DDIM];
  const int t=threadIdx.x, w=t>>6, l=t&63, k=blockIdx.x;
  const int r0=(l>>3)*4, c0=(l&7)*4;

  const float4* cv4 = (const float4*)(cov + (size_t)k*DDIM*DDIM);
  #pragma unroll
  for(int v=0; v<16; v++){
    int idx4 = t + 256*v; float4 f = cv4[idx4];
    int e = idx4*4; int i = e>>7; int j = e&127;
    float* d = &A[i*SA+j]; d[0]=f.x; d[1]=f.y; d[2]=f.z; d[3]=f.w;
  }
  for(int z=t; z<DDIM*SA; z+=256) W[z] = 0.f;
  if(t<DDIM) muS[t] = means[k*DDIM+t];
  __syncthreads();
  if(t<DDIM) A[t*SA+t] += GMM_EPS;
  __syncthreads();

  static const int SYI[10]={1,2,2,3,3,3, 2,3,3, 3};
  static const int SYJ[10]={1,1,2,1,2,3, 2,2,3, 3};
  static const int SYO[5] ={0,6,9,10,10};

  float hsum = 0.f;
  #pragma unroll 1
  for(int b=0;b<4;b++){
    const int b32=b*32;
    if(w==0) hsum += chol_inv32(&A[b32*SA+b32], &W[b32*SA+b32], l&31);
    __syncthreads();
    if(w < 3-b){
      const int ibl = b+1+w;
      float acc[4][4]={};
      for(int kc=0;kc<32;kc+=4){
        float a_[4][4], b_[4][4];
        #pragma unroll
        for(int e=0;e<4;e++)
          #pragma unroll
          for(int g=0;g<4;g++){
            a_[e][g]=A[(32*ibl+r0+e)*SA + b32+kc+g];
            b_[e][g]=W[(b32+c0+e)*SA   + b32+kc+g];
          }
        #pragma unroll
        for(int e=0;e<4;e++)
          #pragma unroll
          for(int f=0;f<4;f++)
            acc[e][f]+=a_[e][0]*b_[f][0]+a_[e][1]*b_[f][1]
                      +a_[e][2]*b_[f][2]+a_[e][3]*b_[f][3];
      }
      #pragma unroll
      for(int e=0;e<4;e++)
        #pragma unroll
        for(int f=0;f<4;f++)
          A[(32*ibl+r0+e)*SA + b32+c0+f] = acc[e][f];
    }
    __syncthreads();
    #pragma unroll 1
    for(int u=SYO[b]+w; u<SYO[b+1]; u+=4){
      const int ui=SYI[u], uj=SYJ[u];
      float acc[4][4]={};
      for(int kc=0;kc<32;kc+=4){
        float a_[4][4], b_[4][4];
        #pragma unroll
        for(int e=0;e<4;e++)
          #pragma unroll
          for(int g=0;g<4;g++){
            a_[e][g]=A[(32*ui+r0+e)*SA + b32+kc+g];
            b_[e][g]=A[(32*uj+c0+e)*SA + b32+kc+g];
          }
        #pragma unroll
        for(int e=0;e<4;e++)
          #pragma unroll
          for(int f=0;f<4;f++)
            acc[e][f]+=a_[e][0]*b_[f][0]+a_[e][1]*b_[f][1]
                      +a_[e][2]*b_[f][2]+a_[e][3]*b_[f][3];
      }
      #pragma unroll
      for(int e=0;e<4;e++)
        #pragma unroll
        for(int f=0;f<4;f++)
          A[(32*ui+r0+e)*SA+32*uj+c0+f] -= acc[e][f];
    }
    __syncthreads();
  }

  #pragma unroll 1
  for(int lev=1;lev<=3;lev++){
    if(w<4-lev){
      const int j=w, i=w+lev;
      float* T=&Tb[w*1056];
      float acc[4][4]={};
      #pragma unroll 1
      for(int p=j;p<i;p++){
        for(int kc=0;kc<32;kc+=4){
          float a_[4][4], b_[4][4];
          #pragma unroll
          for(int e=0;e<4;e++)
            #pragma unroll
            for(int g=0;g<4;g++){
              a_[e][g]=A[(32*i+r0+e)*SA + 32*p+kc+g];
              b_[e][g]=W[(32*p+kc+e)*SA + 32*j+c0+g];
            }
          #pragma unroll
          for(int e=0;e<4;e++)
            #pragma unroll
            for(int f=0;f<4;f++)
              acc[e][f]+=a_[e][0]*b_[0][f]+a_[e][1]*b_[1][f]
                        +a_[e][2]*b_[2][f]+a_[e][3]*b_[3][f];
        }
      }
      #pragma unroll
      for(int e=0;e<4;e++)
        #pragma unroll
        for(int f=0;f<4;f++)
          T[(r0+e)*33+c0+f]=acc[e][f];
      float ac2[4][4]={};
      for(int kc=0;kc<32;kc+=4){
        float a_[4][4], b_[4][4];
        #pragma unroll
        for(int e=0;e<4;e++)
          #pragma unroll
          for(int g=0;g<4;g++){
            a_[e][g]=W[(32*i+r0+e)*SA + 32*i+kc+g];
            b_[e][g]=T[(kc+e)*33 + c0+g];
          }
        #pragma unroll
        for(int e=0;e<4;e++)
          #pragma unroll
          for(int f=0;f<4;f++)
            ac2[e][f]+=a_[e][0]*b_[0][f]+a_[e][1]*b_[1][f]
                      +a_[e][2]*b_[2][f]+a_[e][3]*b_[3][f];
      }
      #pragma unroll
      for(int e=0;e<4;e++)
        #pragma unroll
        for(int f=0;f<4;f++)
          W[(32*i+r0+e)*SA+32*j+c0+f] = -ac2[e][f];
    }
    __syncthreads();
  }

  // ---- m' = U*mu -> Tb[0..127] ----
  if(t<DDIM){
    float s=0.f;
    #pragma unroll 8
    for(int c=0;c<DDIM;c++) s += W[t*SA+c]*muS[c];
    Tb[t]=s;
  }
  __syncthreads();
  // ---- q = U^T m' -> Tb[128..255]  (q[d] = sum_r W[r][d]*m'[r]) ----
  if(t<DDIM){
    float s=0.f;
    #pragma unroll 8
    for(int r=0;r<DDIM;r++) s += W[r*SA+t]*Tb[r];
    Tb[128+t]=s;
  }
  __syncthreads();
  // ---- c3 = log w - hsum - D/2*log(2pi) - 0.5*||m'||^2  (wave 0) ----
  if(w==0){
    float p = Tb[l]*Tb[l] + Tb[l+64]*Tb[l+64];
    #pragma unroll
    for(int off=32; off; off>>=1) p += __shfl_xor(p, off);
    if(l==0) ws_c3[k] = logf(wts[k]) - hsum - 117.6241322f - 0.5f*p;
  }
  // ---- Q A-frag panel: row k of 32x128 panel, 8 kc-tiles; this block fills
  // lanes (half*32 + k) of each tile with bf16 pairs of q.
  if(t<16){
    int tile=t>>1, half=t&1;
    const float* qq=&Tb[128 + tile*16 + half*8];
    unsigned uu[4];
    #pragma unroll
    for(int h2=0;h2<4;h2++){
      unsigned lo=f2bf(qq[2*h2]), hi=f2bf(qq[2*h2+1]);
      uu[h2]=lo|(hi<<16);
    }
    uint4 wv; wv.x=uu[0]; wv.y=uu[1]; wv.z=uu[2]; wv.w=uu[3];
    ((uint4*)qfrag)[tile*64 + half*32 + k] = wv;
  }
  // ---- tight-packed lower-triangular U frags: 20 tiles/comp.
  // tile order: db0:{kc0,1} db1:{kc0..3} db2:{kc0..5} db3:{kc0..7}
  #pragma unroll 1
  for(int s0=t;s0<UFT;s0+=256){
    int tile=s0>>6, l2=s0&63;
    int db = (tile<2)?0:((tile<6)?1:((tile<12)?2:3));
    int kc = tile - ((db==0)?0:((db==1)?2:((db==2)?6:12)));
    int row=db*32+(l2&31), colb=kc*16+((l2>>5)<<3);
    unsigned uu[4];
    #pragma unroll
    for(int h2=0;h2<4;h2++){
      unsigned lo=f2bf(W[row*SA+colb+2*h2]);
      unsigned hi=f2bf(W[row*SA+colb+2*h2+1]);
      uu[h2]=lo|(hi<<16);
    }
    uint4 wv; wv.x=uu[0]; wv.y=uu[1]; wv.z=uu[2]; wv.w=uu[3];
    ((uint4*)ufrag)[(size_t)k*UFT+s0]=wv;
  }
}

// ---------------------------------------------------------------------------
// k_main: 256 thr = 4 waves. Wave w: point-pair pg=w>>1 (2x32 points),
// db-pair sel=w&1 (sel0 -> row-blocks {0,3} = 2+8 kc-steps, sel1 -> {1,2} =
// 4+6) -> exactly 20 MFMAs/comp/wave (62.5% of full, triangular-exact,
// balanced). maha = ||Ux||^2 accumulated; init = -2*q.x via one 8-MFMA GEMM;
// out = c3 - 0.5*maha.
// ---------------------------------------------------------------------------
// frag index: sel0 tiles {0,1, 12..19}, sel1 tiles {2..11}
#define LOADF0(dst, KK) {                                                     \
    const uint4* up = &uf[(size_t)(KK)*UFT];                                  \
    dst[0]=up[lane]; dst[1]=up[64+lane];                                      \
    _Pragma("unroll")                                                         \
    for(int j=2;j<10;j++) dst[j]=up[(j+10)*64+lane];                          \
  }
#define LOADF1(dst, KK) {                                                     \
    const uint4* up = &uf[(size_t)(KK)*UFT];                                  \
    _Pragma("unroll")                                                         \
    for(int j=0;j<10;j++) dst[j]=up[(j+2)*64+lane];                           \
  }
// EXTA = kc extent of first (A) db-block; remaining 10-EXTA frags are B-block.
#define BODY(UR, KK, EXTA) {                                                  \
    f32x16 aA0={},aA1={},aB0={},aB1={};                                       \
    _Pragma("unroll")                                                         \
    for(int c=0;c<8;c++){                                                     \
      if(c<(EXTA)){                                                           \
        bf16x8 fa=__builtin_bit_cast(bf16x8,UR[c]);                           \
        aA0=__builtin_amdgcn_mfma_f32_32x32x16_bf16(fa,xf[0][c],aA0,0,0,0);   \
        aA1=__builtin_amdgcn_mfma_f32_32x32x16_bf16(fa,xf[1][c],aA1,0,0,0);   \
      }                                                                       \
      if(c<10-(EXTA)){                                                        \
        bf16x8 fb=__builtin_bit_cast(bf16x8,UR[(EXTA)+c]);                    \
        aB0=__builtin_amdgcn_mfma_f32_32x32x16_bf16(fb,xf[0][c],aB0,0,0,0);   \
        aB1=__builtin_amdgcn_mfma_f32_32x32x16_bf16(fb,xf[1][c],aB1,0,0,0);   \
      }                                                                       \
    }                                                                         \
    float p0=0.f,p1=0.f,p2=0.f,p3=0.f;                                        \
    _Pragma("unroll")                                                         \
    for(int r=0;r<16;r+=2){                                                   \
      p0=fmaf(aA0[r],aA0[r],p0);     p1=fmaf(aA0[r+1],aA0[r+1],p1);           \
      p2=fmaf(aA1[r],aA1[r],p2);     p3=fmaf(aA1[r+1],aA1[r+1],p3);           \
      p0=fmaf(aB0[r],aB0[r],p0);     p1=fmaf(aB0[r+1],aB0[r+1],p1);           \
      p2=fmaf(aB1[r],aB1[r],p2);     p3=fmaf(aB1[r+1],aB1[r+1],p3);           \
    }                                                                         \
    atomicAdd(&maha[(KK)*DDIM + ptA + ln], p0+p1);                            \
    atomicAdd(&maha[(KK)*DDIM + ptB + ln], p2+p3);                            \
  }

__global__ __launch_bounds__(256,2) void k_main(const float* __restrict__ x,
                                                const uint4* __restrict__ uf,
                                                const uint4* __restrict__ qf,
                                                const float* __restrict__ ws_c3,
                                                float* __restrict__ out){
  __shared__ float maha[KCOMP*DDIM];   // 16 KB [k][n]
  __shared__ float c3s[KCOMP];
  const int t = threadIdx.x, lane = t&63, w = t>>6;
  const int q = lane>>5, ln = lane&31;
  const int pg = w>>1, sel = w&1;
  const size_t n0 = (size_t)blockIdx.x * 128;

  // issue Q-frag loads early (latency hidden under xf pack)
  uint4 qr[8];
  #pragma unroll
  for(int c=0;c<8;c++) qr[c]=qf[c*64+lane];
  if(t < KCOMP) c3s[t] = ws_c3[t];

  // pack x B-frags for this wave's 2 point-tiles (pg*64 .. pg*64+63)
  bf16x8 xf[2][8];
  {
    const float* xb = x + (n0 + (size_t)pg*64)*DDIM + 8*q;
    #pragma unroll
    for(int g=0; g<2; g++){
      const float* rowp = xb + (size_t)(g*32 + ln)*DDIM;
      #pragma unroll
      for(int c=0; c<8; c++){
        float4 f0 = *(const float4*)(rowp + c*16);
        float4 f1 = *(const float4*)(rowp + c*16 + 4);
        union { unsigned short us[8]; bf16x8 v; } cvt;
        cvt.us[0]=f2bf(f0.x); cvt.us[1]=f2bf(f0.y); cvt.us[2]=f2bf(f0.z); cvt.us[3]=f2bf(f0.w);
        cvt.us[4]=f2bf(f1.x); cvt.us[5]=f2bf(f1.y); cvt.us[6]=f2bf(f1.z); cvt.us[7]=f2bf(f1.w);
        xf[g][c] = cvt.v;
      }
    }
  }

  // linear-term init: maha[k][pt] = -2 * (q_k . x_pt). Wave w owns point-tile
  // tl = 2*pg + sel; C layout row=(r&3)+8*(r>>2)+4*q = k, col = ln = point.
  {
    f32x16 aq = {};
    #pragma unroll
    for(int c=0;c<8;c++)
      aq = __builtin_amdgcn_mfma_f32_32x32x16_bf16(
             __builtin_bit_cast(bf16x8, qr[c]), xf[sel][c], aq, 0,0,0);
    const int tl = pg*2 + sel;
    #pragma unroll
    for(int r=0;r<16;r++){
      int row = (r&3) + 8*(r>>2) + 4*q;
      maha[row*DDIM + tl*32 + ln] = -2.f*aq[r];
    }
  }
  __syncthreads();

  const int ptA = pg*64, ptB = pg*64 + 32;
  uint4 uA[10], uB[10];
  if(sel==0){            // db-blocks {0,3}: extents 2 + 8
    LOADF0(uA, 0)
    #pragma unroll 1
    for(int k2=0;k2<KCOMP;k2+=2){
      LOADF0(uB, k2+1)
      BODY(uA, k2, 2)
      LOADF0(uA, (k2+2)&(KCOMP-1))
      BODY(uB, k2+1, 2)
    }
  } else {               // db-blocks {1,2}: extents 4 + 6
    LOADF1(uA, 0)
    #pragma unroll 1
    for(int k2=0;k2<KCOMP;k2+=2){
      LOADF1(uB, k2+1)
      BODY(uA, k2, 4)
      LOADF1(uA, (k2+2)&(KCOMP-1))
      BODY(uB, k2+1, 4)
    }
  }
  __syncthreads();

  if(t < 128){
    float m_run = -INFINITY, s_run = 0.f;
    #pragma unroll 1
    for(int k3=0;k3<KCOMP;k3++){
      float a  = c3s[k3] - 0.5f*maha[k3*DDIM + t];
      float nm = fmaxf(m_run, a);
      s_run = s_run*__expf(m_run-nm) + __expf(a-nm);
      m_run = nm;
    }
    out[n0 + t] = m_run + logf(s_run);
  }
}

// ---------------------------------------------------------------------------
extern "C" void kernel_launch(void* const* d_in, const int* in_sizes, int n_in,
                              void* d_out, int out_size, void* d_ws, size_t ws_size,
                              hipStream_t stream){
  const float* x   = (const float*)d_in[0];
  const float* mu  = (const float*)d_in[1];
  const float* cov = (const float*)d_in[2];
  const float* wts = (const float*)d_in[3];
  float* out = (float*)d_out;
  char*  ws  = (char*)d_ws;

  float*          wsC3 = (float*)ws;                    // 128 B (c3)
  unsigned short* wsQF = (unsigned short*)(ws + 512);   // 8 KB (Q bf16 frags)
  unsigned short* wsUF = (unsigned short*)(ws + 16384); // 640 KB (U bf16 frags, tight)

  k_prep<<<KCOMP, 256, 0, stream>>>(cov, wts, mu, wsC3, wsQF, wsUF);
  k_main<<<NPTS/128, 256, 0, stream>>>(x, (const uint4*)wsUF, (const uint4*)wsQF, wsC3, out);
}

// Round 2
// 215.436 us; speedup vs baseline: 1.0528x; 1.0211x over previous
//
#include <hip/hip_runtime.h>
#include <hip/hip_bf16.h>
#include <math.h>

#define KCOMP 32
#define DDIM  128
#define NPTS  65536
#define GMM_EPS 1e-6f
#define SA 130   // LDS row stride: even -> float2(ds_read_b64) aligned; %32==2 -> bank stride 2 (2-way, free)
#define TA 34    // Tb row stride (even, float2-aligned)
#define UFT 1280 // uint4 per component: 20 nonzero (db,kc) tiles * 64 lanes

typedef __attribute__((ext_vector_type(8)))  __bf16 bf16x8;
typedef __attribute__((ext_vector_type(16))) float  f32x16;

__device__ __forceinline__ unsigned short f2bf(float f){
  unsigned u = __builtin_bit_cast(unsigned, f);
  u = (u + 0x7FFFu + ((u >> 16) & 1u)) >> 16;   // RNE
  return (unsigned short)u;
}
__device__ __forceinline__ float rlane(float v, int lsrc){
  return __builtin_bit_cast(float, __builtin_amdgcn_readlane(__builtin_bit_cast(int, v), lsrc));
}

// ---------------------------------------------------------------------------
// chol_inv32: register-resident Cholesky + triangular inverse of one 32x32
// SPD block (validated). Column reads at SA=130: bank (2i+c)%32, lanes c
// stride 1 -> conflict-free.
// ---------------------------------------------------------------------------
__device__ __noinline__ float chol_inv32(float* __restrict__ Ab,
                                         float* __restrict__ Wb,
                                         const int c){
  float ar[32], lr[32], rd[32], v[32];
  #pragma unroll
  for(int i=0;i<32;i++) ar[i] = Ab[i*SA + c];
  float hl = 0.f;
  #pragma unroll
  for(int j=0;j<32;j++){
    float d   = rlane(ar[j], j);
    float rsd = rsqrtf(d);
    hl += logf(d);
    rd[j] = rsd;
    float Lcj  = ar[j]*rsd;
    lr[j] = (c>=j) ? Lcj : 0.f;
    float coef = Lcj*rsd;
    #pragma unroll
    for(int i=j;i<32;i++){
      float bij = rlane(ar[i], j);
      ar[i] = fmaf(-bij, coef, ar[i]);
    }
  }
  #pragma unroll
  for(int j=0;j<32;j++) Ab[c*SA + j] = lr[j];
  #pragma unroll
  for(int i=0;i<32;i++){
    float s = (i==c) ? 1.f : 0.f;
    #pragma unroll
    for(int p=0;p<i;p++) s = fmaf(-rlane(lr[p], i), v[p], s);
    v[i] = s * rd[i];
  }
  #pragma unroll
  for(int i=0;i<32;i++) Wb[i*SA + c] = v[i];
  return 0.5f*hl;
}

// float2 LDS load helpers (addresses verified even at all call sites)
#define LD2A4(dst, base, row, col) {                                          \
    float2 t0_=*(const float2*)&(base)[(row)*SA + (col)];                     \
    float2 t1_=*(const float2*)&(base)[(row)*SA + (col)+2];                   \
    dst[0]=t0_.x; dst[1]=t0_.y; dst[2]=t1_.x; dst[3]=t1_.y;                   \
  }

// ---------------------------------------------------------------------------
// k_prep: one block (256 thr) per component. Blocked Cholesky+inverse with
// register-resident diag math; panel/SYRK/inverse-level GEMMs now use
// float2 (ds_read_b64) loads/stores -> half the LDS-pipe instructions.
// Tail: m' = U*mu, q = U^T m', c3, Q-frag panel, tight-packed U frags.
// ---------------------------------------------------------------------------
__global__ __launch_bounds__(256) void k_prep(const float* __restrict__ cov,
                                              const float* __restrict__ wts,
                                              const float* __restrict__ means,
                                              float* __restrict__ ws_c3,
                                              unsigned short* __restrict__ qfrag,
                                              unsigned short* __restrict__ ufrag){
  __shared__ __align__(16) float A[DDIM*SA];   // 66.6 KB
  __shared__ __align__(16) float W[DDIM*SA];   // 66.6 KB
  __shared__ __align__(16) float Tb[3*32*TA];  // 13.1 KB; later m'[0..127], q[128..255]
  __shared__ __align__(16) float muS[DDIM];
  const int t=threadIdx.x, w=t>>6, l=t&63, k=blockIdx.x;
  const int r0=(l>>3)*4, c0=(l&7)*4;

  const float4* cv4 = (const float4*)(cov + (size_t)k*DDIM*DDIM);
  #pragma unroll
  for(int v=0; v<16; v++){
    int idx4 = t + 256*v; float4 f = cv4[idx4];
    int e = idx4*4; int i = e>>7; int j = e&127;
    float2* d = (float2*)&A[i*SA+j];
    d[0]=make_float2(f.x,f.y); d[1]=make_float2(f.z,f.w);
  }
  for(int z=t; z<DDIM*SA; z+=256) W[z] = 0.f;
  if(t<DDIM) muS[t] = means[k*DDIM+t];
  __syncthreads();
  if(t<DDIM) A[t*SA+t] += GMM_EPS;
  __syncthreads();

  static const int SYI[10]={1,2,2,3,3,3, 2,3,3, 3};
  static const int SYJ[10]={1,1,2,1,2,3, 2,2,3, 3};
  static const int SYO[5] ={0,6,9,10,10};

  float hsum = 0.f;
  #pragma unroll 1
  for(int b=0;b<4;b++){
    const int b32=b*32;
    if(w==0) hsum += chol_inv32(&A[b32*SA+b32], &W[b32*SA+b32], l&31);
    __syncthreads();
    // ---- panel solve: L_ib = A_ib @ V^T ----
    if(w < 3-b){
      const int ibl = b+1+w;
      float acc[4][4]={};
      for(int kc=0;kc<32;kc+=4){
        float a_[4][4], b_[4][4];
        #pragma unroll
        for(int e=0;e<4;e++){
          LD2A4(a_[e], A, 32*ibl+r0+e, b32+kc)
          LD2A4(b_[e], W, b32+c0+e,    b32+kc)
        }
        #pragma unroll
        for(int e=0;e<4;e++)
          #pragma unroll
          for(int f=0;f<4;f++)
            acc[e][f]+=a_[e][0]*b_[f][0]+a_[e][1]*b_[f][1]
                      +a_[e][2]*b_[f][2]+a_[e][3]*b_[f][3];
      }
      #pragma unroll
      for(int e=0;e<4;e++){
        *(float2*)&A[(32*ibl+r0+e)*SA + b32+c0  ] = make_float2(acc[e][0],acc[e][1]);
        *(float2*)&A[(32*ibl+r0+e)*SA + b32+c0+2] = make_float2(acc[e][2],acc[e][3]);
      }
    }
    __syncthreads();
    // ---- SYRK: A_ij -= L_ib @ L_jb^T ----
    #pragma unroll 1
    for(int u=SYO[b]+w; u<SYO[b+1]; u+=4){
      const int ui=SYI[u], uj=SYJ[u];
      float acc[4][4]={};
      for(int kc=0;kc<32;kc+=4){
        float a_[4][4], b_[4][4];
        #pragma unroll
        for(int e=0;e<4;e++){
          LD2A4(a_[e], A, 32*ui+r0+e, b32+kc)
          LD2A4(b_[e], A, 32*uj+c0+e, b32+kc)
        }
        #pragma unroll
        for(int e=0;e<4;e++)
          #pragma unroll
          for(int f=0;f<4;f++)
            acc[e][f]+=a_[e][0]*b_[f][0]+a_[e][1]*b_[f][1]
                      +a_[e][2]*b_[f][2]+a_[e][3]*b_[f][3];
      }
      #pragma unroll
      for(int e=0;e<4;e++){
        float2* p0=(float2*)&A[(32*ui+r0+e)*SA+32*uj+c0];
        float2 v0=p0[0], v1=p0[1];
        v0.x-=acc[e][0]; v0.y-=acc[e][1]; v1.x-=acc[e][2]; v1.y-=acc[e][3];
        p0[0]=v0; p0[1]=v1;
      }
    }
    __syncthreads();
  }

  // ---- inverse levels: U_ij = -V_i (sum_p L_ip U_pj) ----
  #pragma unroll 1
  for(int lev=1;lev<=3;lev++){
    if(w<4-lev){
      const int j=w, i=w+lev;
      float* T=&Tb[w*32*TA];
      float acc[4][4]={};
      #pragma unroll 1
      for(int p=j;p<i;p++){
        for(int kc=0;kc<32;kc+=4){
          float a_[4][4], b_[4][4];
          #pragma unroll
          for(int e=0;e<4;e++){
            LD2A4(a_[e], A, 32*i+r0+e, 32*p+kc)
            LD2A4(b_[e], W, 32*p+kc+e, 32*j+c0)   // row kc+e, cols c0..c0+3
          }
          #pragma unroll
          for(int e=0;e<4;e++)
            #pragma unroll
            for(int f=0;f<4;f++)
              acc[e][f]+=a_[e][0]*b_[0][f]+a_[e][1]*b_[1][f]
                        +a_[e][2]*b_[2][f]+a_[e][3]*b_[3][f];
        }
      }
      #pragma unroll
      for(int e=0;e<4;e++){
        *(float2*)&T[(r0+e)*TA+c0  ] = make_float2(acc[e][0],acc[e][1]);
        *(float2*)&T[(r0+e)*TA+c0+2] = make_float2(acc[e][2],acc[e][3]);
      }
      float ac2[4][4]={};
      for(int kc=0;kc<32;kc+=4){
        float a_[4][4], b_[4][4];
        #pragma unroll
        for(int e=0;e<4;e++){
          LD2A4(a_[e], W, 32*i+r0+e, 32*i+kc)
          { float2 t0_=*(const float2*)&T[(kc+e)*TA + c0];
            float2 t1_=*(const float2*)&T[(kc+e)*TA + c0+2];
            b_[e][0]=t0_.x; b_[e][1]=t0_.y; b_[e][2]=t1_.x; b_[e][3]=t1_.y; }
        }
        #pragma unroll
        for(int e=0;e<4;e++)
          #pragma unroll
          for(int f=0;f<4;f++)
            ac2[e][f]+=a_[e][0]*b_[0][f]+a_[e][1]*b_[1][f]
                      +a_[e][2]*b_[2][f]+a_[e][3]*b_[3][f];
      }
      #pragma unroll
      for(int e=0;e<4;e++){
        *(float2*)&W[(32*i+r0+e)*SA+32*j+c0  ] = make_float2(-ac2[e][0],-ac2[e][1]);
        *(float2*)&W[(32*i+r0+e)*SA+32*j+c0+2] = make_float2(-ac2[e][2],-ac2[e][3]);
      }
    }
    __syncthreads();
  }

  // ---- m' = U*mu -> Tb[0..127]  (float2 over columns) ----
  if(t<DDIM){
    float s=0.f;
    #pragma unroll 4
    for(int c2=0;c2<64;c2++){
      float2 wv=*(const float2*)&W[t*SA+2*c2];
      float2 mv=*(const float2*)&muS[2*c2];
      s += wv.x*mv.x + wv.y*mv.y;
    }
    Tb[t]=s;
  }
  __syncthreads();
  // ---- q = U^T m' -> Tb[128..255] ----
  if(t<DDIM){
    float s=0.f;
    #pragma unroll 8
    for(int r=0;r<DDIM;r++) s += W[r*SA+t]*Tb[r];
    Tb[128+t]=s;
  }
  __syncthreads();
  // ---- c3 = log w - hsum - D/2*log(2pi) - 0.5*||m'||^2  (wave 0) ----
  if(w==0){
    float p = Tb[l]*Tb[l] + Tb[l+64]*Tb[l+64];
    #pragma unroll
    for(int off=32; off; off>>=1) p += __shfl_xor(p, off);
    if(l==0) ws_c3[k] = logf(wts[k]) - hsum - 117.6241322f - 0.5f*p;
  }
  // ---- Q A-frag panel ----
  if(t<16){
    int tile=t>>1, half=t&1;
    const float* qq=&Tb[128 + tile*16 + half*8];
    unsigned uu[4];
    #pragma unroll
    for(int h2=0;h2<4;h2++){
      unsigned lo=f2bf(qq[2*h2]), hi=f2bf(qq[2*h2+1]);
      uu[h2]=lo|(hi<<16);
    }
    uint4 wv; wv.x=uu[0]; wv.y=uu[1]; wv.z=uu[2]; wv.w=uu[3];
    ((uint4*)qfrag)[tile*64 + half*32 + k] = wv;
  }
  // ---- tight-packed lower-triangular U frags: 20 tiles/comp ----
  #pragma unroll 1
  for(int s0=t;s0<UFT;s0+=256){
    int tile=s0>>6, l2=s0&63;
    int db = (tile<2)?0:((tile<6)?1:((tile<12)?2:3));
    int kc = tile - ((db==0)?0:((db==1)?2:((db==2)?6:12)));
    int row=db*32+(l2&31), colb=kc*16+((l2>>5)<<3);
    unsigned uu[4];
    #pragma unroll
    for(int h2=0;h2<4;h2++){
      float2 wv2=*(const float2*)&W[row*SA+colb+2*h2];
      uu[h2]=f2bf(wv2.x)|(((unsigned)f2bf(wv2.y))<<16);
    }
    uint4 wv; wv.x=uu[0]; wv.y=uu[1]; wv.z=uu[2]; wv.w=uu[3];
    ((uint4*)ufrag)[(size_t)k*UFT+s0]=wv;
  }
}

// ---------------------------------------------------------------------------
// k_main: 64 points/block, 1024 blocks -> 4 blocks/CU (16 waves/CU) for
// latency hiding. Wave w = (pt = w>>1, sel = w&1): one 32-point tile, one
// db-pair (sel0: {db0,db3} = 2+8 kc-tiles; sel1: {db1,db2} = 4+6) -> 10
// MFMAs/comp/wave. Rolling 5+5 uint4 prefetch keeps VGPR <= 128.
// ---------------------------------------------------------------------------
#define TM0(j) ((j)<2 ? (j) : (j)+10)   // sel0 tiles {0,1,12..19}
#define TM1(j) ((j)+2)                  // sel1 tiles {2..11}

#define RUNLOOP(EXTA_, TM) {                                                  \
    const uint4* ufb = uf;                                                    \
    _Pragma("unroll")                                                         \
    for(int j=0;j<5;j++) uA[j]=ufb[(size_t)(TM(j))*64+lane];                  \
    _Pragma("unroll 1")                                                       \
    for(int k2=0;k2<KCOMP;k2++){                                              \
      _Pragma("unroll")                                                       \
      for(int j=0;j<5;j++) uB[j]=ufb[(size_t)(TM(j+5))*64+lane];              \
      const uint4* ufn = uf + (size_t)((k2+1)&(KCOMP-1))*UFT;                 \
      f32x16 aA={}, aB={};                                                    \
      _Pragma("unroll")                                                       \
      for(int j=0;j<5;j++){                                                   \
        bf16x8 fr=__builtin_bit_cast(bf16x8,uA[j]);                           \
        if(j<(EXTA_)) aA=__builtin_amdgcn_mfma_f32_32x32x16_bf16(fr,xf[j],aA,0,0,0); \
        else          aB=__builtin_amdgcn_mfma_f32_32x32x16_bf16(fr,xf[j-(EXTA_)],aB,0,0,0); \
      }                                                                       \
      _Pragma("unroll")                                                       \
      for(int j=0;j<5;j++) uA[j]=ufn[(size_t)(TM(j))*64+lane];                \
      _Pragma("unroll")                                                       \
      for(int j=5;j<10;j++){                                                  \
        bf16x8 fr=__builtin_bit_cast(bf16x8,uB[j-5]);                         \
        aB=__builtin_amdgcn_mfma_f32_32x32x16_bf16(fr,xf[j-(EXTA_)],aB,0,0,0);\
      }                                                                       \
      float p0=0.f,p1=0.f,p2=0.f,p3=0.f;                                      \
      _Pragma("unroll")                                                       \
      for(int r=0;r<16;r+=2){                                                 \
        p0=fmaf(aA[r],aA[r],p0);   p1=fmaf(aA[r+1],aA[r+1],p1);               \
        p2=fmaf(aB[r],aB[r],p2);   p3=fmaf(aB[r+1],aB[r+1],p3);               \
      }                                                                       \
      atomicAdd(&maha[k2*64 + ptb + ln], (p0+p1)+(p2+p3));                    \
      ufb = ufn;                                                              \
    }                                                                         \
  }

__global__ __launch_bounds__(256,4) void k_main(const float* __restrict__ x,
                                                const uint4* __restrict__ uf,
                                                const uint4* __restrict__ qf,
                                                const float* __restrict__ ws_c3,
                                                float* __restrict__ out){
  __shared__ float maha[KCOMP*64];   // 8 KB [k][pt]
  __shared__ float c3s[KCOMP];
  const int t = threadIdx.x, lane = t&63, w = t>>6;
  const int qh = lane>>5, ln = lane&31;
  const int pt = w>>1, sel = w&1, ptb = pt*32;
  const size_t n0 = (size_t)blockIdx.x * 64;

  uint4 qr[8];
  if(sel==0){
    #pragma unroll
    for(int c=0;c<8;c++) qr[c]=qf[c*64+lane];
  }
  if(t < KCOMP) c3s[t] = ws_c3[t];

  // pack x B-frags for this wave's point-tile (rows ptb..ptb+31)
  bf16x8 xf[8];
  {
    const float* rowp = x + (n0 + (size_t)(ptb + ln))*DDIM + 8*qh;
    #pragma unroll
    for(int c=0; c<8; c++){
      float4 f0 = *(const float4*)(rowp + c*16);
      float4 f1 = *(const float4*)(rowp + c*16 + 4);
      union { unsigned short us[8]; bf16x8 v; } cvt;
      cvt.us[0]=f2bf(f0.x); cvt.us[1]=f2bf(f0.y); cvt.us[2]=f2bf(f0.z); cvt.us[3]=f2bf(f0.w);
      cvt.us[4]=f2bf(f1.x); cvt.us[5]=f2bf(f1.y); cvt.us[6]=f2bf(f1.z); cvt.us[7]=f2bf(f1.w);
      xf[c] = cvt.v;
    }
  }

  // linear-term init: maha[k][pt] = -2*(q_k . x_pt), by sel==0 wave of each pt
  if(sel==0){
    f32x16 aq = {};
    #pragma unroll
    for(int c=0;c<8;c++)
      aq = __builtin_amdgcn_mfma_f32_32x32x16_bf16(
             __builtin_bit_cast(bf16x8, qr[c]), xf[c], aq, 0,0,0);
    #pragma unroll
    for(int r=0;r<16;r++){
      int row = (r&3) + 8*(r>>2) + 4*qh;
      maha[row*64 + ptb + ln] = -2.f*aq[r];
    }
  }
  __syncthreads();

  uint4 uA[5], uB[5];
  if(sel==0){ RUNLOOP(2, TM0) } else { RUNLOOP(4, TM1) }
  __syncthreads();

  if(t < 64){
    float m_run = -INFINITY, s_run = 0.f;
    #pragma unroll 1
    for(int k3=0;k3<KCOMP;k3++){
      float a  = c3s[k3] - 0.5f*maha[k3*64 + t];
      float nm = fmaxf(m_run, a);
      s_run = s_run*__expf(m_run-nm) + __expf(a-nm);
      m_run = nm;
    }
    out[n0 + t] = m_run + logf(s_run);
  }
}

// ---------------------------------------------------------------------------
extern "C" void kernel_launch(void* const* d_in, const int* in_sizes, int n_in,
                              void* d_out, int out_size, void* d_ws, size_t ws_size,
                              hipStream_t stream){
  const float* x   = (const float*)d_in[0];
  const float* mu  = (const float*)d_in[1];
  const float* cov = (const float*)d_in[2];
  const float* wts = (const float*)d_in[3];
  float* out = (float*)d_out;
  char*  ws  = (char*)d_ws;

  float*          wsC3 = (float*)ws;                    // 128 B (c3)
  unsigned short* wsQF = (unsigned short*)(ws + 512);   // 8 KB (Q bf16 frags)
  unsigned short* wsUF = (unsigned short*)(ws + 16384); // 640 KB (U bf16 frags, tight)

  k_prep<<<KCOMP, 256, 0, stream>>>(cov, wts, mu, wsC3, wsQF, wsUF);
  k_main<<<NPTS/64, 256, 0, stream>>>(x, (const uint4*)wsUF, (const uint4*)wsQF, wsC3, out);
}

// Round 3
// 207.891 us; speedup vs baseline: 1.0910x; 1.0363x over previous
//
#include <hip/hip_runtime.h>
#include <hip/hip_bf16.h>
#include <math.h>

#define KCOMP 32
#define DDIM  128
#define NPTS  65536
#define GMM_EPS 1e-6f
#define SA 129   // LDS row stride (odd -> conflict-free for scalar col access)
#define UFT 1280 // uint4 per component: 20 nonzero (db,kc) tiles * 64 lanes

typedef __attribute__((ext_vector_type(8)))  __bf16 bf16x8;
typedef __attribute__((ext_vector_type(16))) float  f32x16;

__device__ __forceinline__ unsigned short f2bf(float f){
  unsigned u = __builtin_bit_cast(unsigned, f);
  u = (u + 0x7FFFu + ((u >> 16) & 1u)) >> 16;   // RNE
  return (unsigned short)u;
}
__device__ __forceinline__ float rlane(float v, int lsrc){
  return __builtin_bit_cast(float, __builtin_amdgcn_readlane(__builtin_bit_cast(int, v), lsrc));
}

// ---------------------------------------------------------------------------
// chol_inv32: register-resident Cholesky + triangular inverse of one 32x32
// SPD block (validated round-1 version, SA=129).
// ---------------------------------------------------------------------------
__device__ __noinline__ float chol_inv32(float* __restrict__ Ab,
                                         float* __restrict__ Wb,
                                         const int c){
  float ar[32], lr[32], rd[32], v[32];
  #pragma unroll
  for(int i=0;i<32;i++) ar[i] = Ab[i*SA + c];
  float hl = 0.f;
  #pragma unroll
  for(int j=0;j<32;j++){
    float d   = rlane(ar[j], j);
    float rsd = rsqrtf(d);
    hl += logf(d);
    rd[j] = rsd;
    float Lcj  = ar[j]*rsd;
    lr[j] = (c>=j) ? Lcj : 0.f;
    float coef = Lcj*rsd;
    #pragma unroll
    for(int i=j;i<32;i++){
      float bij = rlane(ar[i], j);
      ar[i] = fmaf(-bij, coef, ar[i]);
    }
  }
  #pragma unroll
  for(int j=0;j<32;j++) Ab[c*SA + j] = lr[j];
  #pragma unroll
  for(int i=0;i<32;i++){
    float s = (i==c) ? 1.f : 0.f;
    #pragma unroll
    for(int p=0;p<i;p++) s = fmaf(-rlane(lr[p], i), v[p], s);
    v[i] = s * rd[i];
  }
  #pragma unroll
  for(int i=0;i<32;i++) Wb[i*SA + c] = v[i];
  return 0.5f*hl;
}

// ---------------------------------------------------------------------------
// k_prep: EXACT round-1 version (measured 86 us; the float2/SA=130 variant
// regressed to 170 us — latency-bound phase lost ILP). One block per comp.
// ---------------------------------------------------------------------------
__global__ __launch_bounds__(256) void k_prep(const float* __restrict__ cov,
                                              const float* __restrict__ wts,
                                              const float* __restrict__ means,
                                              float* __restrict__ ws_c3,
                                              unsigned short* __restrict__ qfrag,
                                              unsigned short* __restrict__ ufrag){
  __shared__ float A[DDIM*SA];      // 64.5 KB: cov -> L (lower)
  __shared__ float W[DDIM*SA];      // 64.5 KB: U = L^{-1} (lower), 0 above
  __shared__ float Tb[3*32*33];     // scratch; later holds m' [0..127], q [128..255]
  __shared__ float muS[DDIM];
  const int t=threadIdx.x, w=t>>6, l=t&63, k=blockIdx.x;
  const int r0=(l>>3)*4, c0=(l&7)*4;

  const float4* cv4 = (const float4*)(cov + (size_t)k*DDIM*DDIM);
  #pragma unroll
  for(int v=0; v<16; v++){
    int idx4 = t + 256*v; float4 f = cv4[idx4];
    int e = idx4*4; int i = e>>7; int j = e&127;
    float* d = &A[i*SA+j]; d[0]=f.x; d[1]=f.y; d[2]=f.z; d[3]=f.w;
  }
  for(int z=t; z<DDIM*SA; z+=256) W[z] = 0.f;
  if(t<DDIM) muS[t] = means[k*DDIM+t];
  __syncthreads();
  if(t<DDIM) A[t*SA+t] += GMM_EPS;
  __syncthreads();

  static const int SYI[10]={1,2,2,3,3,3, 2,3,3, 3};
  static const int SYJ[10]={1,1,2,1,2,3, 2,2,3, 3};
  static const int SYO[5] ={0,6,9,10,10};

  float hsum = 0.f;
  #pragma unroll 1
  for(int b=0;b<4;b++){
    const int b32=b*32;
    if(w==0) hsum += chol_inv32(&A[b32*SA+b32], &W[b32*SA+b32], l&31);
    __syncthreads();
    if(w < 3-b){
      const int ibl = b+1+w;
      float acc[4][4]={};
      for(int kc=0;kc<32;kc+=4){
        float a_[4][4], b_[4][4];
        #pragma unroll
        for(int e=0;e<4;e++)
          #pragma unroll
          for(int g=0;g<4;g++){
            a_[e][g]=A[(32*ibl+r0+e)*SA + b32+kc+g];
            b_[e][g]=W[(b32+c0+e)*SA   + b32+kc+g];
          }
        #pragma unroll
        for(int e=0;e<4;e++)
          #pragma unroll
          for(int f=0;f<4;f++)
            acc[e][f]+=a_[e][0]*b_[f][0]+a_[e][1]*b_[f][1]
                      +a_[e][2]*b_[f][2]+a_[e][3]*b_[f][3];
      }
      #pragma unroll
      for(int e=0;e<4;e++)
        #pragma unroll
        for(int f=0;f<4;f++)
          A[(32*ibl+r0+e)*SA + b32+c0+f] = acc[e][f];
    }
    __syncthreads();
    #pragma unroll 1
    for(int u=SYO[b]+w; u<SYO[b+1]; u+=4){
      const int ui=SYI[u], uj=SYJ[u];
      float acc[4][4]={};
      for(int kc=0;kc<32;kc+=4){
        float a_[4][4], b_[4][4];
        #pragma unroll
        for(int e=0;e<4;e++)
          #pragma unroll
          for(int g=0;g<4;g++){
            a_[e][g]=A[(32*ui+r0+e)*SA + b32+kc+g];
            b_[e][g]=A[(32*uj+c0+e)*SA + b32+kc+g];
          }
        #pragma unroll
        for(int e=0;e<4;e++)
          #pragma unroll
          for(int f=0;f<4;f++)
            acc[e][f]+=a_[e][0]*b_[f][0]+a_[e][1]*b_[f][1]
                      +a_[e][2]*b_[f][2]+a_[e][3]*b_[f][3];
      }
      #pragma unroll
      for(int e=0;e<4;e++)
        #pragma unroll
        for(int f=0;f<4;f++)
          A[(32*ui+r0+e)*SA+32*uj+c0+f] -= acc[e][f];
    }
    __syncthreads();
  }

  #pragma unroll 1
  for(int lev=1;lev<=3;lev++){
    if(w<4-lev){
      const int j=w, i=w+lev;
      float* T=&Tb[w*1056];
      float acc[4][4]={};
      #pragma unroll 1
      for(int p=j;p<i;p++){
        for(int kc=0;kc<32;kc+=4){
          float a_[4][4], b_[4][4];
          #pragma unroll
          for(int e=0;e<4;e++)
            #pragma unroll
            for(int g=0;g<4;g++){
              a_[e][g]=A[(32*i+r0+e)*SA + 32*p+kc+g];
              b_[e][g]=W[(32*p+kc+e)*SA + 32*j+c0+g];
            }
          #pragma unroll
          for(int e=0;e<4;e++)
            #pragma unroll
            for(int f=0;f<4;f++)
              acc[e][f]+=a_[e][0]*b_[0][f]+a_[e][1]*b_[1][f]
                        +a_[e][2]*b_[2][f]+a_[e][3]*b_[3][f];
        }
      }
      #pragma unroll
      for(int e=0;e<4;e++)
        #pragma unroll
        for(int f=0;f<4;f++)
          T[(r0+e)*33+c0+f]=acc[e][f];
      float ac2[4][4]={};
      for(int kc=0;kc<32;kc+=4){
        float a_[4][4], b_[4][4];
        #pragma unroll
        for(int e=0;e<4;e++)
          #pragma unroll
          for(int g=0;g<4;g++){
            a_[e][g]=W[(32*i+r0+e)*SA + 32*i+kc+g];
            b_[e][g]=T[(kc+e)*33 + c0+g];
          }
        #pragma unroll
        for(int e=0;e<4;e++)
          #pragma unroll
          for(int f=0;f<4;f++)
            ac2[e][f]+=a_[e][0]*b_[0][f]+a_[e][1]*b_[1][f]
                      +a_[e][2]*b_[2][f]+a_[e][3]*b_[3][f];
      }
      #pragma unroll
      for(int e=0;e<4;e++)
        #pragma unroll
        for(int f=0;f<4;f++)
          W[(32*i+r0+e)*SA+32*j+c0+f] = -ac2[e][f];
    }
    __syncthreads();
  }

  // ---- m' = U*mu -> Tb[0..127] ----
  if(t<DDIM){
    float s=0.f;
    #pragma unroll 8
    for(int c=0;c<DDIM;c++) s += W[t*SA+c]*muS[c];
    Tb[t]=s;
  }
  __syncthreads();
  // ---- q = U^T m' -> Tb[128..255]  (q[d] = sum_r W[r][d]*m'[r]) ----
  if(t<DDIM){
    float s=0.f;
    #pragma unroll 8
    for(int r=0;r<DDIM;r++) s += W[r*SA+t]*Tb[r];
    Tb[128+t]=s;
  }
  __syncthreads();
  // ---- c3 = log w - hsum - D/2*log(2pi) - 0.5*||m'||^2  (wave 0) ----
  if(w==0){
    float p = Tb[l]*Tb[l] + Tb[l+64]*Tb[l+64];
    #pragma unroll
    for(int off=32; off; off>>=1) p += __shfl_xor(p, off);
    if(l==0) ws_c3[k] = logf(wts[k]) - hsum - 117.6241322f - 0.5f*p;
  }
  // ---- Q A-frag panel ----
  if(t<16){
    int tile=t>>1, half=t&1;
    const float* qq=&Tb[128 + tile*16 + half*8];
    unsigned uu[4];
    #pragma unroll
    for(int h2=0;h2<4;h2++){
      unsigned lo=f2bf(qq[2*h2]), hi=f2bf(qq[2*h2+1]);
      uu[h2]=lo|(hi<<16);
    }
    uint4 wv; wv.x=uu[0]; wv.y=uu[1]; wv.z=uu[2]; wv.w=uu[3];
    ((uint4*)qfrag)[tile*64 + half*32 + k] = wv;
  }
  // ---- tight-packed lower-triangular U frags: 20 tiles/comp ----
  #pragma unroll 1
  for(int s0=t;s0<UFT;s0+=256){
    int tile=s0>>6, l2=s0&63;
    int db = (tile<2)?0:((tile<6)?1:((tile<12)?2:3));
    int kc = tile - ((db==0)?0:((db==1)?2:((db==2)?6:12)));
    int row=db*32+(l2&31), colb=kc*16+((l2>>5)<<3);
    unsigned uu[4];
    #pragma unroll
    for(int h2=0;h2<4;h2++){
      unsigned lo=f2bf(W[row*SA+colb+2*h2]);
      unsigned hi=f2bf(W[row*SA+colb+2*h2+1]);
      uu[h2]=lo|(hi<<16);
    }
    uint4 wv; wv.x=uu[0]; wv.y=uu[1]; wv.z=uu[2]; wv.w=uu[3];
    ((uint4*)ufrag)[(size_t)k*UFT+s0]=wv;
  }
}

// ---------------------------------------------------------------------------
// k_main: round-2 version (measured ~45 us steady): 64 points/block, 1024
// blocks -> 4 blocks/CU (16 waves/CU). Wave w = (pt = w>>1, sel = w&1):
// one 32-point tile, one db-pair (sel0: {db0,db3} = 2+8 kc-tiles; sel1:
// {db1,db2} = 4+6) -> 10 MFMAs/comp/wave. Rolling 5+5 uint4 prefetch.
// ---------------------------------------------------------------------------
#define TM0(j) ((j)<2 ? (j) : (j)+10)   // sel0 tiles {0,1,12..19}
#define TM1(j) ((j)+2)                  // sel1 tiles {2..11}

#define RUNLOOP(EXTA_, TM) {                                                  \
    const uint4* ufb = uf;                                                    \
    _Pragma("unroll")                                                         \
    for(int j=0;j<5;j++) uA[j]=ufb[(size_t)(TM(j))*64+lane];                  \
    _Pragma("unroll 1")                                                       \
    for(int k2=0;k2<KCOMP;k2++){                                              \
      _Pragma("unroll")                                                       \
      for(int j=0;j<5;j++) uB[j]=ufb[(size_t)(TM(j+5))*64+lane];              \
      const uint4* ufn = uf + (size_t)((k2+1)&(KCOMP-1))*UFT;                 \
      f32x16 aA={}, aB={};                                                    \
      _Pragma("unroll")                                                       \
      for(int j=0;j<5;j++){                                                   \
        bf16x8 fr=__builtin_bit_cast(bf16x8,uA[j]);                           \
        if(j<(EXTA_)) aA=__builtin_amdgcn_mfma_f32_32x32x16_bf16(fr,xf[j],aA,0,0,0); \
        else          aB=__builtin_amdgcn_mfma_f32_32x32x16_bf16(fr,xf[j-(EXTA_)],aB,0,0,0); \
      }                                                                       \
      _Pragma("unroll")                                                       \
      for(int j=0;j<5;j++) uA[j]=ufn[(size_t)(TM(j))*64+lane];                \
      _Pragma("unroll")                                                       \
      for(int j=5;j<10;j++){                                                  \
        bf16x8 fr=__builtin_bit_cast(bf16x8,uB[j-5]);                         \
        aB=__builtin_amdgcn_mfma_f32_32x32x16_bf16(fr,xf[j-(EXTA_)],aB,0,0,0);\
      }                                                                       \
      float p0=0.f,p1=0.f,p2=0.f,p3=0.f;                                      \
      _Pragma("unroll")                                                       \
      for(int r=0;r<16;r+=2){                                                 \
        p0=fmaf(aA[r],aA[r],p0);   p1=fmaf(aA[r+1],aA[r+1],p1);               \
        p2=fmaf(aB[r],aB[r],p2);   p3=fmaf(aB[r+1],aB[r+1],p3);               \
      }                                                                       \
      atomicAdd(&maha[k2*64 + ptb + ln], (p0+p1)+(p2+p3));                    \
      ufb = ufn;                                                              \
    }                                                                         \
  }

__global__ __launch_bounds__(256,4) void k_main(const float* __restrict__ x,
                                                const uint4* __restrict__ uf,
                                                const uint4* __restrict__ qf,
                                                const float* __restrict__ ws_c3,
                                                float* __restrict__ out){
  __shared__ float maha[KCOMP*64];   // 8 KB [k][pt]
  __shared__ float c3s[KCOMP];
  const int t = threadIdx.x, lane = t&63, w = t>>6;
  const int qh = lane>>5, ln = lane&31;
  const int pt = w>>1, sel = w&1, ptb = pt*32;
  const size_t n0 = (size_t)blockIdx.x * 64;

  uint4 qr[8];
  if(sel==0){
    #pragma unroll
    for(int c=0;c<8;c++) qr[c]=qf[c*64+lane];
  }
  if(t < KCOMP) c3s[t] = ws_c3[t];

  // pack x B-frags for this wave's point-tile (rows ptb..ptb+31)
  bf16x8 xf[8];
  {
    const float* rowp = x + (n0 + (size_t)(ptb + ln))*DDIM + 8*qh;
    #pragma unroll
    for(int c=0; c<8; c++){
      float4 f0 = *(const float4*)(rowp + c*16);
      float4 f1 = *(const float4*)(rowp + c*16 + 4);
      union { unsigned short us[8]; bf16x8 v; } cvt;
      cvt.us[0]=f2bf(f0.x); cvt.us[1]=f2bf(f0.y); cvt.us[2]=f2bf(f0.z); cvt.us[3]=f2bf(f0.w);
      cvt.us[4]=f2bf(f1.x); cvt.us[5]=f2bf(f1.y); cvt.us[6]=f2bf(f1.z); cvt.us[7]=f2bf(f1.w);
      xf[c] = cvt.v;
    }
  }

  // linear-term init: maha[k][pt] = -2*(q_k . x_pt), by sel==0 wave of each pt
  if(sel==0){
    f32x16 aq = {};
    #pragma unroll
    for(int c=0;c<8;c++)
      aq = __builtin_amdgcn_mfma_f32_32x32x16_bf16(
             __builtin_bit_cast(bf16x8, qr[c]), xf[c], aq, 0,0,0);
    #pragma unroll
    for(int r=0;r<16;r++){
      int row = (r&3) + 8*(r>>2) + 4*qh;
      maha[row*64 + ptb + ln] = -2.f*aq[r];
    }
  }
  __syncthreads();

  uint4 uA[5], uB[5];
  if(sel==0){ RUNLOOP(2, TM0) } else { RUNLOOP(4, TM1) }
  __syncthreads();

  if(t < 64){
    float m_run = -INFINITY, s_run = 0.f;
    #pragma unroll 1
    for(int k3=0;k3<KCOMP;k3++){
      float a  = c3s[k3] - 0.5f*maha[k3*64 + t];
      float nm = fmaxf(m_run, a);
      s_run = s_run*__expf(m_run-nm) + __expf(a-nm);
      m_run = nm;
    }
    out[n0 + t] = m_run + logf(s_run);
  }
}

// ---------------------------------------------------------------------------
extern "C" void kernel_launch(void* const* d_in, const int* in_sizes, int n_in,
                              void* d_out, int out_size, void* d_ws, size_t ws_size,
                              hipStream_t stream){
  const float* x   = (const float*)d_in[0];
  const float* mu  = (const float*)d_in[1];
  const float* cov = (const float*)d_in[2];
  const float* wts = (const float*)d_in[3];
  float* out = (float*)d_out;
  char*  ws  = (char*)d_ws;

  float*          wsC3 = (float*)ws;                    // 128 B (c3)
  unsigned short* wsQF = (unsigned short*)(ws + 512);   // 8 KB (Q bf16 frags)
  unsigned short* wsUF = (unsigned short*)(ws + 16384); // 640 KB (U bf16 frags, tight)

  k_prep<<<KCOMP, 256, 0, stream>>>(cov, wts, mu, wsC3, wsQF, wsUF);
  k_main<<<NPTS/64, 256, 0, stream>>>(x, (const uint4*)wsUF, (const uint4*)wsQF, wsC3, out);
}

// Round 4
// 196.300 us; speedup vs baseline: 1.1554x; 1.0590x over previous
//
#include <hip/hip_runtime.h>
#include <hip/hip_bf16.h>
#include <math.h>

#define KCOMP 32
#define DDIM  128
#define NPTS  65536
#define GMM_EPS 1e-6f
#define SA 129   // LDS row stride (odd -> conflict-free for scalar col access)
#define UFT 1280 // uint4 per component: 20 nonzero (db,kc) tiles * 64 lanes

typedef __attribute__((ext_vector_type(8)))  __bf16 bf16x8;
typedef __attribute__((ext_vector_type(16))) float  f32x16;

__device__ __forceinline__ unsigned short f2bf(float f){
  unsigned u = __builtin_bit_cast(unsigned, f);
  u = (u + 0x7FFFu + ((u >> 16) & 1u)) >> 16;   // RNE
  return (unsigned short)u;
}
__device__ __forceinline__ float rlane(float v, int lsrc){
  return __builtin_bit_cast(float, __builtin_amdgcn_readlane(__builtin_bit_cast(int, v), lsrc));
}

// ---------------------------------------------------------------------------
// chol_inv32: register-resident Cholesky + triangular inverse of one 32x32
// SPD block (validated round-1 version, SA=129).
// ---------------------------------------------------------------------------
__device__ __noinline__ float chol_inv32(float* __restrict__ Ab,
                                         float* __restrict__ Wb,
                                         const int c){
  float ar[32], lr[32], rd[32], v[32];
  #pragma unroll
  for(int i=0;i<32;i++) ar[i] = Ab[i*SA + c];
  float hl = 0.f;
  #pragma unroll
  for(int j=0;j<32;j++){
    float d   = rlane(ar[j], j);
    float rsd = rsqrtf(d);
    hl += logf(d);
    rd[j] = rsd;
    float Lcj  = ar[j]*rsd;
    lr[j] = (c>=j) ? Lcj : 0.f;
    float coef = Lcj*rsd;
    #pragma unroll
    for(int i=j;i<32;i++){
      float bij = rlane(ar[i], j);
      ar[i] = fmaf(-bij, coef, ar[i]);
    }
  }
  #pragma unroll
  for(int j=0;j<32;j++) Ab[c*SA + j] = lr[j];
  #pragma unroll
  for(int i=0;i<32;i++){
    float s = (i==c) ? 1.f : 0.f;
    #pragma unroll
    for(int p=0;p<i;p++) s = fmaf(-rlane(lr[p], i), v[p], s);
    v[i] = s * rd[i];
  }
  #pragma unroll
  for(int i=0;i<32;i++) Wb[i*SA + c] = v[i];
  return 0.5f*hl;
}

// ---------------------------------------------------------------------------
// k_prep: EXACT round-3 version (measured ~83 us). One block per component.
// ---------------------------------------------------------------------------
__global__ __launch_bounds__(256) void k_prep(const float* __restrict__ cov,
                                              const float* __restrict__ wts,
                                              const float* __restrict__ means,
                                              float* __restrict__ ws_c3,
                                              unsigned short* __restrict__ qfrag,
                                              unsigned short* __restrict__ ufrag){
  __shared__ float A[DDIM*SA];      // 64.5 KB: cov -> L (lower)
  __shared__ float W[DDIM*SA];      // 64.5 KB: U = L^{-1} (lower), 0 above
  __shared__ float Tb[3*32*33];     // scratch; later holds m' [0..127], q [128..255]
  __shared__ float muS[DDIM];
  const int t=threadIdx.x, w=t>>6, l=t&63, k=blockIdx.x;
  const int r0=(l>>3)*4, c0=(l&7)*4;

  const float4* cv4 = (const float4*)(cov + (size_t)k*DDIM*DDIM);
  #pragma unroll
  for(int v=0; v<16; v++){
    int idx4 = t + 256*v; float4 f = cv4[idx4];
    int e = idx4*4; int i = e>>7; int j = e&127;
    float* d = &A[i*SA+j]; d[0]=f.x; d[1]=f.y; d[2]=f.z; d[3]=f.w;
  }
  for(int z=t; z<DDIM*SA; z+=256) W[z] = 0.f;
  if(t<DDIM) muS[t] = means[k*DDIM+t];
  __syncthreads();
  if(t<DDIM) A[t*SA+t] += GMM_EPS;
  __syncthreads();

  static const int SYI[10]={1,2,2,3,3,3, 2,3,3, 3};
  static const int SYJ[10]={1,1,2,1,2,3, 2,2,3, 3};
  static const int SYO[5] ={0,6,9,10,10};

  float hsum = 0.f;
  #pragma unroll 1
  for(int b=0;b<4;b++){
    const int b32=b*32;
    if(w==0) hsum += chol_inv32(&A[b32*SA+b32], &W[b32*SA+b32], l&31);
    __syncthreads();
    if(w < 3-b){
      const int ibl = b+1+w;
      float acc[4][4]={};
      for(int kc=0;kc<32;kc+=4){
        float a_[4][4], b_[4][4];
        #pragma unroll
        for(int e=0;e<4;e++)
          #pragma unroll
          for(int g=0;g<4;g++){
            a_[e][g]=A[(32*ibl+r0+e)*SA + b32+kc+g];
            b_[e][g]=W[(b32+c0+e)*SA   + b32+kc+g];
          }
        #pragma unroll
        for(int e=0;e<4;e++)
          #pragma unroll
          for(int f=0;f<4;f++)
            acc[e][f]+=a_[e][0]*b_[f][0]+a_[e][1]*b_[f][1]
                      +a_[e][2]*b_[f][2]+a_[e][3]*b_[f][3];
      }
      #pragma unroll
      for(int e=0;e<4;e++)
        #pragma unroll
        for(int f=0;f<4;f++)
          A[(32*ibl+r0+e)*SA + b32+c0+f] = acc[e][f];
    }
    __syncthreads();
    #pragma unroll 1
    for(int u=SYO[b]+w; u<SYO[b+1]; u+=4){
      const int ui=SYI[u], uj=SYJ[u];
      float acc[4][4]={};
      for(int kc=0;kc<32;kc+=4){
        float a_[4][4], b_[4][4];
        #pragma unroll
        for(int e=0;e<4;e++)
          #pragma unroll
          for(int g=0;g<4;g++){
            a_[e][g]=A[(32*ui+r0+e)*SA + b32+kc+g];
            b_[e][g]=A[(32*uj+c0+e)*SA + b32+kc+g];
          }
        #pragma unroll
        for(int e=0;e<4;e++)
          #pragma unroll
          for(int f=0;f<4;f++)
            acc[e][f]+=a_[e][0]*b_[f][0]+a_[e][1]*b_[f][1]
                      +a_[e][2]*b_[f][2]+a_[e][3]*b_[f][3];
      }
      #pragma unroll
      for(int e=0;e<4;e++)
        #pragma unroll
        for(int f=0;f<4;f++)
          A[(32*ui+r0+e)*SA+32*uj+c0+f] -= acc[e][f];
    }
    __syncthreads();
  }

  #pragma unroll 1
  for(int lev=1;lev<=3;lev++){
    if(w<4-lev){
      const int j=w, i=w+lev;
      float* T=&Tb[w*1056];
      float acc[4][4]={};
      #pragma unroll 1
      for(int p=j;p<i;p++){
        for(int kc=0;kc<32;kc+=4){
          float a_[4][4], b_[4][4];
          #pragma unroll
          for(int e=0;e<4;e++)
            #pragma unroll
            for(int g=0;g<4;g++){
              a_[e][g]=A[(32*i+r0+e)*SA + 32*p+kc+g];
              b_[e][g]=W[(32*p+kc+e)*SA + 32*j+c0+g];
            }
          #pragma unroll
          for(int e=0;e<4;e++)
            #pragma unroll
            for(int f=0;f<4;f++)
              acc[e][f]+=a_[e][0]*b_[0][f]+a_[e][1]*b_[1][f]
                        +a_[e][2]*b_[2][f]+a_[e][3]*b_[3][f];
        }
      }
      #pragma unroll
      for(int e=0;e<4;e++)
        #pragma unroll
        for(int f=0;f<4;f++)
          T[(r0+e)*33+c0+f]=acc[e][f];
      float ac2[4][4]={};
      for(int kc=0;kc<32;kc+=4){
        float a_[4][4], b_[4][4];
        #pragma unroll
        for(int e=0;e<4;e++)
          #pragma unroll
          for(int g=0;g<4;g++){
            a_[e][g]=W[(32*i+r0+e)*SA + 32*i+kc+g];
            b_[e][g]=T[(kc+e)*33 + c0+g];
          }
        #pragma unroll
        for(int e=0;e<4;e++)
          #pragma unroll
          for(int f=0;f<4;f++)
            ac2[e][f]+=a_[e][0]*b_[0][f]+a_[e][1]*b_[1][f]
                      +a_[e][2]*b_[2][f]+a_[e][3]*b_[3][f];
      }
      #pragma unroll
      for(int e=0;e<4;e++)
        #pragma unroll
        for(int f=0;f<4;f++)
          W[(32*i+r0+e)*SA+32*j+c0+f] = -ac2[e][f];
    }
    __syncthreads();
  }

  // ---- m' = U*mu -> Tb[0..127] ----
  if(t<DDIM){
    float s=0.f;
    #pragma unroll 8
    for(int c=0;c<DDIM;c++) s += W[t*SA+c]*muS[c];
    Tb[t]=s;
  }
  __syncthreads();
  // ---- q = U^T m' -> Tb[128..255]  (q[d] = sum_r W[r][d]*m'[r]) ----
  if(t<DDIM){
    float s=0.f;
    #pragma unroll 8
    for(int r=0;r<DDIM;r++) s += W[r*SA+t]*Tb[r];
    Tb[128+t]=s;
  }
  __syncthreads();
  // ---- c3 = log w - hsum - D/2*log(2pi) - 0.5*||m'||^2  (wave 0) ----
  if(w==0){
    float p = Tb[l]*Tb[l] + Tb[l+64]*Tb[l+64];
    #pragma unroll
    for(int off=32; off; off>>=1) p += __shfl_xor(p, off);
    if(l==0) ws_c3[k] = logf(wts[k]) - hsum - 117.6241322f - 0.5f*p;
  }
  // ---- Q A-frag panel ----
  if(t<16){
    int tile=t>>1, half=t&1;
    const float* qq=&Tb[128 + tile*16 + half*8];
    unsigned uu[4];
    #pragma unroll
    for(int h2=0;h2<4;h2++){
      unsigned lo=f2bf(qq[2*h2]), hi=f2bf(qq[2*h2+1]);
      uu[h2]=lo|(hi<<16);
    }
    uint4 wv; wv.x=uu[0]; wv.y=uu[1]; wv.z=uu[2]; wv.w=uu[3];
    ((uint4*)qfrag)[tile*64 + half*32 + k] = wv;
  }
  // ---- tight-packed lower-triangular U frags: 20 tiles/comp ----
  #pragma unroll 1
  for(int s0=t;s0<UFT;s0+=256){
    int tile=s0>>6, l2=s0&63;
    int db = (tile<2)?0:((tile<6)?1:((tile<12)?2:3));
    int kc = tile - ((db==0)?0:((db==1)?2:((db==2)?6:12)));
    int row=db*32+(l2&31), colb=kc*16+((l2>>5)<<3);
    unsigned uu[4];
    #pragma unroll
    for(int h2=0;h2<4;h2++){
      unsigned lo=f2bf(W[row*SA+colb+2*h2]);
      unsigned hi=f2bf(W[row*SA+colb+2*h2+1]);
      uu[h2]=lo|(hi<<16);
    }
    uint4 wv; wv.x=uu[0]; wv.y=uu[1]; wv.z=uu[2]; wv.w=uu[3];
    ((uint4*)ufrag)[(size_t)k*UFT+s0]=wv;
  }
}

// ---------------------------------------------------------------------------
// k_main (NEW, comp-resident U): 512 thr = 8 waves; block owns 128 points
// (4 pt-tiles) staged ONCE in LDS as bf16 MFMA B-frags. Wave w processes
// comps {w, w+8, w+16, w+24}: per comp, all 20 triangular U tiles live in
// 80 VGPR (loaded once from L2), swept over the 4 pt-tiles. Linear term
// -2 q.x for all 32 comps via one 8-MFMA q-panel GEMM per tile (prologue).
// Online logsumexp merged in LDS per 8-comp group. U L2 traffic: 2.6 GB ->
// 327 MB (was the ~75 us wall); x read exactly once.
// ---------------------------------------------------------------------------
#define MFMA_B(acc,u,xv) acc=__builtin_amdgcn_mfma_f32_32x32x16_bf16(__builtin_bit_cast(bf16x8,u),xv,acc,0,0,0)

__global__ __launch_bounds__(512,2) void k_main(const float* __restrict__ x,
                                                const uint4* __restrict__ uf,
                                                const uint4* __restrict__ qf,
                                                const float* __restrict__ ws_c3,
                                                float* __restrict__ out){
  __shared__ uint4 xs[4*8*64];      // 32 KB: x bf16 frags [tile][c][lane]
  __shared__ float lin[KCOMP*128];  // 16 KB: -2 q.x [comp][pt]
  __shared__ float mahaS[8*128];    // 4 KB:  ||Ux||^2 [wave][pt]
  __shared__ float c3s[KCOMP];
  const int t=threadIdx.x, lane=t&63, w=t>>6;
  const int qh=lane>>5, ln=lane&31;
  const size_t n0=(size_t)blockIdx.x*128;

  if(t<KCOMP) c3s[t]=ws_c3[t];

  // ---- stage 128 points of x -> bf16 frag layout in LDS (once) ----
  {
    const float* xb = x + n0*DDIM;
    #pragma unroll
    for(int j=0;j<8;j++){
      int idx = j*512 + t;               // float4 index in 128x128 block
      int n = idx & 127, d0 = (idx>>7)*4;
      float4 f = *(const float4*)(xb + (size_t)n*DDIM + d0);
      unsigned lo = f2bf(f.x) | (((unsigned)f2bf(f.y))<<16);
      unsigned hi = f2bf(f.z) | (((unsigned)f2bf(f.w))<<16);
      int tile=n>>5, lnn=n&31, c=d0>>4, qq=(d0>>3)&1, e4=d0&7;
      *(uint2*)((char*)xs + tile*8192 + c*1024 + qq*512 + lnn*16 + e4*2)
          = make_uint2(lo,hi);
    }
  }
  __syncthreads();

  // ---- prologue: lin[k][pt] = -2 q_k . x_pt (waves 0-3, tile = w) ----
  if(w<4){
    f32x16 aq={};
    #pragma unroll
    for(int c=0;c<8;c++){
      uint4 qr = qf[c*64+lane];
      bf16x8 xq = __builtin_bit_cast(bf16x8, xs[w*512 + c*64 + lane]);
      MFMA_B(aq, qr, xq);
    }
    #pragma unroll
    for(int r=0;r<16;r++){
      int row=(r&3)+8*(r>>2)+4*qh;       // row = comp (validated C-layout)
      lin[row*128 + w*32 + ln] = -2.f*aq[r];
    }
  }
  __syncthreads();

  float m_run=-INFINITY, s_run=0.f;

  #pragma unroll 1
  for(int iter=0;iter<4;iter++){
    const int k = iter*8 + w;
    uint4 ur[20];
    #pragma unroll
    for(int j=0;j<20;j++) ur[j]=uf[(size_t)k*UFT + j*64 + lane];

    #pragma unroll 1
    for(int tile=0;tile<4;tile++){
      bf16x8 xf[8];
      #pragma unroll
      for(int c=0;c<8;c++) xf[c]=__builtin_bit_cast(bf16x8, xs[tile*512 + c*64 + lane]);
      f32x16 a0={},a1={},a2={},a3={};
      #pragma unroll
      for(int c=0;c<2;c++) MFMA_B(a0, ur[c],    xf[c]);   // db0: kc 0..1
      #pragma unroll
      for(int c=0;c<4;c++) MFMA_B(a1, ur[2+c],  xf[c]);   // db1: kc 0..3
      #pragma unroll
      for(int c=0;c<6;c++) MFMA_B(a2, ur[6+c],  xf[c]);   // db2: kc 0..5
      #pragma unroll
      for(int c=0;c<8;c++) MFMA_B(a3, ur[12+c], xf[c]);   // db3: kc 0..7
      float p0=0.f,p1=0.f,p2=0.f,p3=0.f;
      #pragma unroll
      for(int r=0;r<16;r+=2){
        p0=fmaf(a0[r],a0[r],p0); p1=fmaf(a0[r+1],a0[r+1],p1);
        p2=fmaf(a1[r],a1[r],p2); p3=fmaf(a1[r+1],a1[r+1],p3);
        p0=fmaf(a2[r],a2[r],p0); p1=fmaf(a2[r+1],a2[r+1],p1);
        p2=fmaf(a3[r],a3[r],p2); p3=fmaf(a3[r+1],a3[r+1],p3);
      }
      float p=(p0+p1)+(p2+p3);
      p += __shfl_xor(p,32);             // fold qh halves (other 16 rows/db)
      if(qh==0) mahaS[w*128 + tile*32 + ln] = p;
    }
    __syncthreads();
    if(t<128){
      #pragma unroll
      for(int c8=0;c8<8;c8++){
        int k2=iter*8+c8;
        float a  = c3s[k2] - 0.5f*(mahaS[c8*128+t] + lin[k2*128+t]);
        float nm = fmaxf(m_run,a);
        s_run = s_run*__expf(m_run-nm)+__expf(a-nm);
        m_run = nm;
      }
    }
    __syncthreads();   // before next iter overwrites mahaS
  }
  if(t<128) out[n0+t] = m_run + logf(s_run);
}

// ---------------------------------------------------------------------------
extern "C" void kernel_launch(void* const* d_in, const int* in_sizes, int n_in,
                              void* d_out, int out_size, void* d_ws, size_t ws_size,
                              hipStream_t stream){
  const float* x   = (const float*)d_in[0];
  const float* mu  = (const float*)d_in[1];
  const float* cov = (const float*)d_in[2];
  const float* wts = (const float*)d_in[3];
  float* out = (float*)d_out;
  char*  ws  = (char*)d_ws;

  float*          wsC3 = (float*)ws;                    // 128 B (c3)
  unsigned short* wsQF = (unsigned short*)(ws + 512);   // 8 KB (Q bf16 frags)
  unsigned short* wsUF = (unsigned short*)(ws + 16384); // 640 KB (U bf16 frags, tight)

  k_prep<<<KCOMP, 256, 0, stream>>>(cov, wts, mu, wsC3, wsQF, wsUF);
  k_main<<<NPTS/128, 512, 0, stream>>>(x, (const uint4*)wsUF, (const uint4*)wsQF, wsC3, out);
}

// Round 5
// 193.522 us; speedup vs baseline: 1.1720x; 1.0144x over previous
//
#include <hip/hip_runtime.h>
#include <hip/hip_bf16.h>
#include <math.h>

#define KCOMP 32
#define DDIM  128
#define NPTS  65536
#define GMM_EPS 1e-6f
#define SA 129   // LDS row stride (odd -> conflict-free for scalar col access)
#define UFT 1280 // uint4 per component: 20 nonzero (db,kc) tiles * 64 lanes

typedef __attribute__((ext_vector_type(8)))  __bf16 bf16x8;
typedef __attribute__((ext_vector_type(16))) float  f32x16;

__device__ __forceinline__ unsigned short f2bf(float f){
  unsigned u = __builtin_bit_cast(unsigned, f);
  u = (u + 0x7FFFu + ((u >> 16) & 1u)) >> 16;   // RNE
  return (unsigned short)u;
}
__device__ __forceinline__ float rlane(float v, int lsrc){
  return __builtin_bit_cast(float, __builtin_amdgcn_readlane(__builtin_bit_cast(int, v), lsrc));
}

// ---------------------------------------------------------------------------
// chol_inv32: register-resident Cholesky + triangular inverse of one 32x32
// SPD block (validated round-1 version, SA=129).
// ---------------------------------------------------------------------------
__device__ __noinline__ float chol_inv32(float* __restrict__ Ab,
                                         float* __restrict__ Wb,
                                         const int c){
  float ar[32], lr[32], rd[32], v[32];
  #pragma unroll
  for(int i=0;i<32;i++) ar[i] = Ab[i*SA + c];
  float hl = 0.f;
  #pragma unroll
  for(int j=0;j<32;j++){
    float d   = rlane(ar[j], j);
    float rsd = rsqrtf(d);
    hl += logf(d);
    rd[j] = rsd;
    float Lcj  = ar[j]*rsd;
    lr[j] = (c>=j) ? Lcj : 0.f;
    float coef = Lcj*rsd;
    #pragma unroll
    for(int i=j;i<32;i++){
      float bij = rlane(ar[i], j);
      ar[i] = fmaf(-bij, coef, ar[i]);
    }
  }
  #pragma unroll
  for(int j=0;j<32;j++) Ab[c*SA + j] = lr[j];
  #pragma unroll
  for(int i=0;i<32;i++){
    float s = (i==c) ? 1.f : 0.f;
    #pragma unroll
    for(int p=0;p<i;p++) s = fmaf(-rlane(lr[p], i), v[p], s);
    v[i] = s * rd[i];
  }
  #pragma unroll
  for(int i=0;i<32;i++) Wb[i*SA + c] = v[i];
  return 0.5f*hl;
}

// ---------------------------------------------------------------------------
// k_prep: EXACT round-3/4 version (measured ~85 us). One block per component.
// ---------------------------------------------------------------------------
__global__ __launch_bounds__(256) void k_prep(const float* __restrict__ cov,
                                              const float* __restrict__ wts,
                                              const float* __restrict__ means,
                                              float* __restrict__ ws_c3,
                                              unsigned short* __restrict__ qfrag,
                                              unsigned short* __restrict__ ufrag){
  __shared__ float A[DDIM*SA];      // 64.5 KB: cov -> L (lower)
  __shared__ float W[DDIM*SA];      // 64.5 KB: U = L^{-1} (lower), 0 above
  __shared__ float Tb[3*32*33];     // scratch; later holds m' [0..127], q [128..255]
  __shared__ float muS[DDIM];
  const int t=threadIdx.x, w=t>>6, l=t&63, k=blockIdx.x;
  const int r0=(l>>3)*4, c0=(l&7)*4;

  const float4* cv4 = (const float4*)(cov + (size_t)k*DDIM*DDIM);
  #pragma unroll
  for(int v=0; v<16; v++){
    int idx4 = t + 256*v; float4 f = cv4[idx4];
    int e = idx4*4; int i = e>>7; int j = e&127;
    float* d = &A[i*SA+j]; d[0]=f.x; d[1]=f.y; d[2]=f.z; d[3]=f.w;
  }
  for(int z=t; z<DDIM*SA; z+=256) W[z] = 0.f;
  if(t<DDIM) muS[t] = means[k*DDIM+t];
  __syncthreads();
  if(t<DDIM) A[t*SA+t] += GMM_EPS;
  __syncthreads();

  static const int SYI[10]={1,2,2,3,3,3, 2,3,3, 3};
  static const int SYJ[10]={1,1,2,1,2,3, 2,2,3, 3};
  static const int SYO[5] ={0,6,9,10,10};

  float hsum = 0.f;
  #pragma unroll 1
  for(int b=0;b<4;b++){
    const int b32=b*32;
    if(w==0) hsum += chol_inv32(&A[b32*SA+b32], &W[b32*SA+b32], l&31);
    __syncthreads();
    if(w < 3-b){
      const int ibl = b+1+w;
      float acc[4][4]={};
      for(int kc=0;kc<32;kc+=4){
        float a_[4][4], b_[4][4];
        #pragma unroll
        for(int e=0;e<4;e++)
          #pragma unroll
          for(int g=0;g<4;g++){
            a_[e][g]=A[(32*ibl+r0+e)*SA + b32+kc+g];
            b_[e][g]=W[(b32+c0+e)*SA   + b32+kc+g];
          }
        #pragma unroll
        for(int e=0;e<4;e++)
          #pragma unroll
          for(int f=0;f<4;f++)
            acc[e][f]+=a_[e][0]*b_[f][0]+a_[e][1]*b_[f][1]
                      +a_[e][2]*b_[f][2]+a_[e][3]*b_[f][3];
      }
      #pragma unroll
      for(int e=0;e<4;e++)
        #pragma unroll
        for(int f=0;f<4;f++)
          A[(32*ibl+r0+e)*SA + b32+c0+f] = acc[e][f];
    }
    __syncthreads();
    #pragma unroll 1
    for(int u=SYO[b]+w; u<SYO[b+1]; u+=4){
      const int ui=SYI[u], uj=SYJ[u];
      float acc[4][4]={};
      for(int kc=0;kc<32;kc+=4){
        float a_[4][4], b_[4][4];
        #pragma unroll
        for(int e=0;e<4;e++)
          #pragma unroll
          for(int g=0;g<4;g++){
            a_[e][g]=A[(32*ui+r0+e)*SA + b32+kc+g];
            b_[e][g]=A[(32*uj+c0+e)*SA + b32+kc+g];
          }
        #pragma unroll
        for(int e=0;e<4;e++)
          #pragma unroll
          for(int f=0;f<4;f++)
            acc[e][f]+=a_[e][0]*b_[f][0]+a_[e][1]*b_[f][1]
                      +a_[e][2]*b_[f][2]+a_[e][3]*b_[f][3];
      }
      #pragma unroll
      for(int e=0;e<4;e++)
        #pragma unroll
        for(int f=0;f<4;f++)
          A[(32*ui+r0+e)*SA+32*uj+c0+f] -= acc[e][f];
    }
    __syncthreads();
  }

  #pragma unroll 1
  for(int lev=1;lev<=3;lev++){
    if(w<4-lev){
      const int j=w, i=w+lev;
      float* T=&Tb[w*1056];
      float acc[4][4]={};
      #pragma unroll 1
      for(int p=j;p<i;p++){
        for(int kc=0;kc<32;kc+=4){
          float a_[4][4], b_[4][4];
          #pragma unroll
          for(int e=0;e<4;e++)
            #pragma unroll
            for(int g=0;g<4;g++){
              a_[e][g]=A[(32*i+r0+e)*SA + 32*p+kc+g];
              b_[e][g]=W[(32*p+kc+e)*SA + 32*j+c0+g];
            }
          #pragma unroll
          for(int e=0;e<4;e++)
            #pragma unroll
            for(int f=0;f<4;f++)
              acc[e][f]+=a_[e][0]*b_[0][f]+a_[e][1]*b_[1][f]
                        +a_[e][2]*b_[2][f]+a_[e][3]*b_[3][f];
        }
      }
      #pragma unroll
      for(int e=0;e<4;e++)
        #pragma unroll
        for(int f=0;f<4;f++)
          T[(r0+e)*33+c0+f]=acc[e][f];
      float ac2[4][4]={};
      for(int kc=0;kc<32;kc+=4){
        float a_[4][4], b_[4][4];
        #pragma unroll
        for(int e=0;e<4;e++)
          #pragma unroll
          for(int g=0;g<4;g++){
            a_[e][g]=W[(32*i+r0+e)*SA + 32*i+kc+g];
            b_[e][g]=T[(kc+e)*33 + c0+g];
          }
        #pragma unroll
        for(int e=0;e<4;e++)
          #pragma unroll
          for(int f=0;f<4;f++)
            ac2[e][f]+=a_[e][0]*b_[0][f]+a_[e][1]*b_[1][f]
                      +a_[e][2]*b_[2][f]+a_[e][3]*b_[3][f];
      }
      #pragma unroll
      for(int e=0;e<4;e++)
        #pragma unroll
        for(int f=0;f<4;f++)
          W[(32*i+r0+e)*SA+32*j+c0+f] = -ac2[e][f];
    }
    __syncthreads();
  }

  // ---- m' = U*mu -> Tb[0..127] ----
  if(t<DDIM){
    float s=0.f;
    #pragma unroll 8
    for(int c=0;c<DDIM;c++) s += W[t*SA+c]*muS[c];
    Tb[t]=s;
  }
  __syncthreads();
  // ---- q = U^T m' -> Tb[128..255]  (q[d] = sum_r W[r][d]*m'[r]) ----
  if(t<DDIM){
    float s=0.f;
    #pragma unroll 8
    for(int r=0;r<DDIM;r++) s += W[r*SA+t]*Tb[r];
    Tb[128+t]=s;
  }
  __syncthreads();
  // ---- c3 = log w - hsum - D/2*log(2pi) - 0.5*||m'||^2  (wave 0) ----
  if(w==0){
    float p = Tb[l]*Tb[l] + Tb[l+64]*Tb[l+64];
    #pragma unroll
    for(int off=32; off; off>>=1) p += __shfl_xor(p, off);
    if(l==0) ws_c3[k] = logf(wts[k]) - hsum - 117.6241322f - 0.5f*p;
  }
  // ---- Q A-frag panel ----
  if(t<16){
    int tile=t>>1, half=t&1;
    const float* qq=&Tb[128 + tile*16 + half*8];
    unsigned uu[4];
    #pragma unroll
    for(int h2=0;h2<4;h2++){
      unsigned lo=f2bf(qq[2*h2]), hi=f2bf(qq[2*h2+1]);
      uu[h2]=lo|(hi<<16);
    }
    uint4 wv; wv.x=uu[0]; wv.y=uu[1]; wv.z=uu[2]; wv.w=uu[3];
    ((uint4*)qfrag)[tile*64 + half*32 + k] = wv;
  }
  // ---- tight-packed lower-triangular U frags: 20 tiles/comp ----
  #pragma unroll 1
  for(int s0=t;s0<UFT;s0+=256){
    int tile=s0>>6, l2=s0&63;
    int db = (tile<2)?0:((tile<6)?1:((tile<12)?2:3));
    int kc = tile - ((db==0)?0:((db==1)?2:((db==2)?6:12)));
    int row=db*32+(l2&31), colb=kc*16+((l2>>5)<<3);
    unsigned uu[4];
    #pragma unroll
    for(int h2=0;h2<4;h2++){
      unsigned lo=f2bf(W[row*SA+colb+2*h2]);
      unsigned hi=f2bf(W[row*SA+colb+2*h2+1]);
      uu[h2]=lo|(hi<<16);
    }
    uint4 wv; wv.x=uu[0]; wv.y=uu[1]; wv.z=uu[2]; wv.w=uu[3];
    ((uint4*)ufrag)[(size_t)k*UFT+s0]=wv;
  }
}

// ---------------------------------------------------------------------------
// k_main (R5: barrier-free comp loop): 512 thr = 8 waves; 128 points/block
// staged ONCE in LDS as bf16 B-frags. Wave w sweeps comps {w,w+8,w+16,w+24}
// with all 20 triangular U tiles register-resident per comp. KEY CHANGE vs
// R4: mahaS is [iter][wave][pt] so NO barriers inside the comp loop — waves
// desync freely, each wave's U-load latency hides under the other waves'
// MFMA streams (we are at 2 waves/SIMD: ~192 VGPR > 128-cliff, checked
// alternatives re-inflate L2 or LDS traffic). Single logsumexp epilogue.
// ---------------------------------------------------------------------------
#define MFMA_B(acc,u,xv) acc=__builtin_amdgcn_mfma_f32_32x32x16_bf16(__builtin_bit_cast(bf16x8,u),xv,acc,0,0,0)

__global__ __launch_bounds__(512,2) void k_main(const float* __restrict__ x,
                                                const uint4* __restrict__ uf,
                                                const uint4* __restrict__ qf,
                                                const float* __restrict__ ws_c3,
                                                float* __restrict__ out){
  __shared__ uint4 xs[4*8*64];       // 32 KB: x bf16 frags [tile][c][lane]
  __shared__ float lin[KCOMP*128];   // 16 KB: -2 q.x [comp][pt]
  __shared__ float mahaS[4*8*128];   // 16 KB: ||Ux||^2 [iter][wave][pt]
  __shared__ float c3s[KCOMP];
  const int t=threadIdx.x, lane=t&63, w=t>>6;
  const int qh=lane>>5, ln=lane&31;
  const size_t n0=(size_t)blockIdx.x*128;

  if(t<KCOMP) c3s[t]=ws_c3[t];

  // ---- stage 128 points of x -> bf16 frag layout in LDS (once) ----
  {
    const float* xb = x + n0*DDIM;
    #pragma unroll
    for(int j=0;j<8;j++){
      int idx = j*512 + t;               // float4 index in 128x128 block
      int n = idx & 127, d0 = (idx>>7)*4;
      float4 f = *(const float4*)(xb + (size_t)n*DDIM + d0);
      unsigned lo = f2bf(f.x) | (((unsigned)f2bf(f.y))<<16);
      unsigned hi = f2bf(f.z) | (((unsigned)f2bf(f.w))<<16);
      int tile=n>>5, lnn=n&31, c=d0>>4, qq=(d0>>3)&1, e4=d0&7;
      *(uint2*)((char*)xs + tile*8192 + c*1024 + qq*512 + lnn*16 + e4*2)
          = make_uint2(lo,hi);
    }
  }
  __syncthreads();   // barrier #1: xs ready (also covers c3s)

  // ---- prologue: lin[k][pt] = -2 q_k . x_pt (waves 0-3, tile = w) ----
  if(w<4){
    f32x16 aq={};
    #pragma unroll
    for(int c=0;c<8;c++){
      uint4 qr = qf[c*64+lane];
      bf16x8 xq = __builtin_bit_cast(bf16x8, xs[w*512 + c*64 + lane]);
      MFMA_B(aq, qr, xq);
    }
    #pragma unroll
    for(int r=0;r<16;r++){
      int row=(r&3)+8*(r>>2)+4*qh;       // row = comp (validated C-layout)
      lin[row*128 + w*32 + ln] = -2.f*aq[r];
    }
  }

  // ---- comp loop: NO barriers. Each (iter,wave) owns mahaS slot. ----
  #pragma unroll 1
  for(int iter=0;iter<4;iter++){
    const int k = iter*8 + w;
    uint4 ur[20];
    #pragma unroll
    for(int j=0;j<20;j++) ur[j]=uf[(size_t)k*UFT + j*64 + lane];

    #pragma unroll 1
    for(int tile=0;tile<4;tile++){
      bf16x8 xf[8];
      #pragma unroll
      for(int c=0;c<8;c++) xf[c]=__builtin_bit_cast(bf16x8, xs[tile*512 + c*64 + lane]);
      f32x16 a0={},a1={},a2={},a3={};
      #pragma unroll
      for(int c=0;c<2;c++) MFMA_B(a0, ur[c],    xf[c]);   // db0: kc 0..1
      #pragma unroll
      for(int c=0;c<4;c++) MFMA_B(a1, ur[2+c],  xf[c]);   // db1: kc 0..3
      #pragma unroll
      for(int c=0;c<6;c++) MFMA_B(a2, ur[6+c],  xf[c]);   // db2: kc 0..5
      #pragma unroll
      for(int c=0;c<8;c++) MFMA_B(a3, ur[12+c], xf[c]);   // db3: kc 0..7
      float p0=0.f,p1=0.f,p2=0.f,p3=0.f;
      #pragma unroll
      for(int r=0;r<16;r+=2){
        p0=fmaf(a0[r],a0[r],p0); p1=fmaf(a0[r+1],a0[r+1],p1);
        p2=fmaf(a1[r],a1[r],p2); p3=fmaf(a1[r+1],a1[r+1],p3);
        p0=fmaf(a2[r],a2[r],p0); p1=fmaf(a2[r+1],a2[r+1],p1);
        p2=fmaf(a3[r],a3[r],p2); p3=fmaf(a3[r+1],a3[r+1],p3);
      }
      float p=(p0+p1)+(p2+p3);
      p += __shfl_xor(p,32);             // fold qh halves (other 16 rows/db)
      if(qh==0) mahaS[iter*1024 + w*128 + tile*32 + ln] = p;
    }
  }
  __syncthreads();   // barrier #2: all mahaS + lin ready

  // ---- single logsumexp epilogue over all 32 comps ----
  if(t<128){
    float m_run=-INFINITY, s_run=0.f;
    #pragma unroll 1
    for(int k3=0;k3<KCOMP;k3++){
      float a  = c3s[k3] - 0.5f*(mahaS[(k3>>3)*1024 + (k3&7)*128 + t] + lin[k3*128 + t]);
      float nm = fmaxf(m_run,a);
      s_run = s_run*__expf(m_run-nm)+__expf(a-nm);
      m_run = nm;
    }
    out[n0+t] = m_run + logf(s_run);
  }
}

// ---------------------------------------------------------------------------
extern "C" void kernel_launch(void* const* d_in, const int* in_sizes, int n_in,
                              void* d_out, int out_size, void* d_ws, size_t ws_size,
                              hipStream_t stream){
  const float* x   = (const float*)d_in[0];
  const float* mu  = (const float*)d_in[1];
  const float* cov = (const float*)d_in[2];
  const float* wts = (const float*)d_in[3];
  float* out = (float*)d_out;
  char*  ws  = (char*)d_ws;

  float*          wsC3 = (float*)ws;                    // 128 B (c3)
  unsigned short* wsQF = (unsigned short*)(ws + 512);   // 8 KB (Q bf16 frags)
  unsigned short* wsUF = (unsigned short*)(ws + 16384); // 640 KB (U bf16 frags, tight)

  k_prep<<<KCOMP, 256, 0, stream>>>(cov, wts, mu, wsC3, wsQF, wsUF);
  k_main<<<NPTS/128, 512, 0, stream>>>(x, (const uint4*)wsUF, (const uint4*)wsQF, wsC3, out);
}

// Round 6
// 171.282 us; speedup vs baseline: 1.3241x; 1.1298x over previous
//
#include <hip/hip_runtime.h>
#include <hip/hip_bf16.h>
#include <math.h>

#define KCOMP 32
#define DDIM  128
#define NPTS  65536
#define GMM_EPS 1e-6f
#define SA 129   // LDS row stride (odd -> conflict-free for scalar col access)
#define UFT 1280 // uint4 per component: 20 nonzero (db,kc) tiles * 64 lanes

typedef __attribute__((ext_vector_type(8)))  __bf16 bf16x8;
typedef __attribute__((ext_vector_type(16))) float  f32x16;

__device__ __forceinline__ unsigned short f2bf(float f){
  unsigned u = __builtin_bit_cast(unsigned, f);
  u = (u + 0x7FFFu + ((u >> 16) & 1u)) >> 16;   // RNE
  return (unsigned short)u;
}
__device__ __forceinline__ float rlane(float v, int lsrc){
  return __builtin_bit_cast(float, __builtin_amdgcn_readlane(__builtin_bit_cast(int, v), lsrc));
}

// ---------------------------------------------------------------------------
// chol_inv32 (R6): register Cholesky + triangular inverse, 32x32, lane c =
// column c. CHANGES vs validated R1 version: (1) logf moved OFF the serial
// j-loop — lane extracts its own diag via predicated select, single logf at
// end (returns per-lane log L[c][c]; caller reduces lanes 0-31). (2) forward
// substitution is RIGHT-LOOKING: per j, v_j = s_j*rd_j then parallel updates
// s_i -= L[i][j]*v_j — critical path 32 short steps instead of ~500 chained
// fmafs. Math identical (same ops, reassociated only across independent i).
// ---------------------------------------------------------------------------
__device__ __noinline__ float chol_inv32(float* __restrict__ Ab,
                                         float* __restrict__ Wb,
                                         const int c){
  float ar[32], lr[32], rd[32], s[32];
  #pragma unroll
  for(int i=0;i<32;i++) ar[i] = Ab[i*SA + c];
  float mydiag = 1.f;
  #pragma unroll
  for(int j=0;j<32;j++){
    float d   = rlane(ar[j], j);
    float rsd = rsqrtf(d);
    rd[j] = rsd;
    float Lcj  = ar[j]*rsd;
    lr[j] = (c>=j) ? Lcj : 0.f;
    if(c==j) mydiag = Lcj;              // = sqrt(d), off critical path
    float coef = Lcj*rsd;
    #pragma unroll
    for(int i=j+1;i<32;i++){
      float bij = rlane(ar[i], j);
      ar[i] = fmaf(-bij, coef, ar[i]);
    }
  }
  #pragma unroll
  for(int j=0;j<32;j++) Ab[c*SA + j] = lr[j];
  // right-looking forward substitution: column c of V = L^{-1}
  #pragma unroll
  for(int i=0;i<32;i++) s[i] = (i==c) ? 1.f : 0.f;
  #pragma unroll
  for(int j=0;j<32;j++){
    float vj = s[j]*rd[j];
    s[j] = vj;
    #pragma unroll
    for(int i=j+1;i<32;i++)
      s[i] = fmaf(-rlane(lr[j], i), vj, s[i]);
  }
  #pragma unroll
  for(int i=0;i<32;i++) Wb[i*SA + c] = s[i];
  return logf(mydiag);
}

// ---- GEMM unit bodies: byte-identical math to R1-R5, parameterized ----
__device__ __forceinline__ void panel_unit(float* __restrict__ A, const float* __restrict__ W,
                                           int r0, int c0, int b, int ibl){
  const int b32=b*32;
  float acc[4][4]={};
  for(int kc=0;kc<32;kc+=4){
    float a_[4][4], b_[4][4];
    #pragma unroll
    for(int e=0;e<4;e++)
      #pragma unroll
      for(int g=0;g<4;g++){
        a_[e][g]=A[(32*ibl+r0+e)*SA + b32+kc+g];
        b_[e][g]=W[(b32+c0+e)*SA   + b32+kc+g];
      }
    #pragma unroll
    for(int e=0;e<4;e++)
      #pragma unroll
      for(int f=0;f<4;f++)
        acc[e][f]+=a_[e][0]*b_[f][0]+a_[e][1]*b_[f][1]
                  +a_[e][2]*b_[f][2]+a_[e][3]*b_[f][3];
  }
  #pragma unroll
  for(int e=0;e<4;e++)
    #pragma unroll
    for(int f=0;f<4;f++)
      A[(32*ibl+r0+e)*SA + b32+c0+f] = acc[e][f];
}

__device__ __forceinline__ void syrk_unit(float* __restrict__ A,
                                          int r0, int c0, int b, int ui, int uj){
  const int b32=b*32;
  float acc[4][4]={};
  for(int kc=0;kc<32;kc+=4){
    float a_[4][4], b_[4][4];
    #pragma unroll
    for(int e=0;e<4;e++)
      #pragma unroll
      for(int g=0;g<4;g++){
        a_[e][g]=A[(32*ui+r0+e)*SA + b32+kc+g];
        b_[e][g]=A[(32*uj+c0+e)*SA + b32+kc+g];
      }
    #pragma unroll
    for(int e=0;e<4;e++)
      #pragma unroll
      for(int f=0;f<4;f++)
        acc[e][f]+=a_[e][0]*b_[f][0]+a_[e][1]*b_[f][1]
                  +a_[e][2]*b_[f][2]+a_[e][3]*b_[f][3];
  }
  #pragma unroll
  for(int e=0;e<4;e++)
    #pragma unroll
    for(int f=0;f<4;f++)
      A[(32*ui+r0+e)*SA+32*uj+c0+f] -= acc[e][f];
}

__device__ __forceinline__ void tg_unit(const float* __restrict__ A, const float* __restrict__ W,
                                        float* __restrict__ T, int r0, int c0, int i, int j){
  float acc[4][4]={};
  #pragma unroll 1
  for(int p=j;p<i;p++){
    for(int kc=0;kc<32;kc+=4){
      float a_[4][4], b_[4][4];
      #pragma unroll
      for(int e=0;e<4;e++)
        #pragma unroll
        for(int g=0;g<4;g++){
          a_[e][g]=A[(32*i+r0+e)*SA + 32*p+kc+g];
          b_[e][g]=W[(32*p+kc+e)*SA + 32*j+c0+g];
        }
      #pragma unroll
      for(int e=0;e<4;e++)
        #pragma unroll
        for(int f=0;f<4;f++)
          acc[e][f]+=a_[e][0]*b_[0][f]+a_[e][1]*b_[1][f]
                    +a_[e][2]*b_[2][f]+a_[e][3]*b_[3][f];
    }
  }
  #pragma unroll
  for(int e=0;e<4;e++)
    #pragma unroll
    for(int f=0;f<4;f++)
      T[(r0+e)*33+c0+f]=acc[e][f];
}

__device__ __forceinline__ void a2_unit(float* __restrict__ W, const float* __restrict__ T,
                                        int r0, int c0, int i, int j){
  float ac2[4][4]={};
  for(int kc=0;kc<32;kc+=4){
    float a_[4][4], b_[4][4];
    #pragma unroll
    for(int e=0;e<4;e++)
      #pragma unroll
      for(int g=0;g<4;g++){
        a_[e][g]=W[(32*i+r0+e)*SA + 32*i+kc+g];
        b_[e][g]=T[(kc+e)*33 + c0+g];
      }
    #pragma unroll
    for(int e=0;e<4;e++)
      #pragma unroll
      for(int f=0;f<4;f++)
        ac2[e][f]+=a_[e][0]*b_[0][f]+a_[e][1]*b_[1][f]
                  +a_[e][2]*b_[2][f]+a_[e][3]*b_[3][f];
  }
  #pragma unroll
  for(int e=0;e<4;e++)
    #pragma unroll
    for(int f=0;f<4;f++)
      W[(32*i+r0+e)*SA+32*j+c0+f] = -ac2[e][f];
}

__device__ __forceinline__ void pack_tile(const float* __restrict__ W,
                                          uint4* __restrict__ uf4, int tile, int l){
  int db = (tile<2)?0:((tile<6)?1:((tile<12)?2:3));
  int kc = tile - ((db==0)?0:((db==1)?2:((db==2)?6:12)));
  int row=db*32+(l&31), colb=kc*16+((l>>5)<<3);
  unsigned uu[4];
  #pragma unroll
  for(int h2=0;h2<4;h2++){
    unsigned lo=f2bf(W[row*SA+colb+2*h2]);
    unsigned hi=f2bf(W[row*SA+colb+2*h2+1]);
    uu[h2]=lo|(hi<<16);
  }
  uint4 wv; wv.x=uu[0]; wv.y=uu[1]; wv.z=uu[2]; wv.w=uu[3];
  uf4[tile*64 + l] = wv;
}

// ---------------------------------------------------------------------------
// k_prep (R6): DAG-scheduled phases. chol of block b overlaps SYRK-rest /
// T-GEMMs / m' of earlier blocks (SYRK split diag-first so the next chol's
// input is ready one phase early). All GEMM unit bodies unchanged. Phase
// read/write block-disjointness verified pairwise.
// ---------------------------------------------------------------------------
__global__ __launch_bounds__(256) void k_prep(const float* __restrict__ cov,
                                              const float* __restrict__ wts,
                                              const float* __restrict__ means,
                                              float* __restrict__ ws_c3,
                                              unsigned short* __restrict__ qfrag,
                                              unsigned short* __restrict__ ufrag){
  __shared__ float A[DDIM*SA];      // 64.5 KB: cov -> L (lower)
  __shared__ float W[DDIM*SA];      // 64.5 KB: U = L^{-1} (lower), 0 above
  __shared__ float Tb[3*1056];      // 12.4 KB: T slots, slot j for T_{i,j}
  __shared__ float muS[DDIM];
  __shared__ float mq[256];         // m' [0..127], q [128..255]
  const int t=threadIdx.x, w=t>>6, l=t&63, k=blockIdx.x;
  const int r0=(l>>3)*4, c0=(l&7)*4;
  uint4* ufK = (uint4*)ufrag + (size_t)k*UFT;

  // Ph0: load cov->A, zero W, stage mu
  const float4* cv4 = (const float4*)(cov + (size_t)k*DDIM*DDIM);
  #pragma unroll
  for(int v=0; v<16; v++){
    int idx4 = t + 256*v; float4 f = cv4[idx4];
    int e = idx4*4; int i = e>>7; int j = e&127;
    float* d = &A[i*SA+j]; d[0]=f.x; d[1]=f.y; d[2]=f.z; d[3]=f.w;
  }
  for(int z=t; z<DDIM*SA; z+=256) W[z] = 0.f;
  if(t<DDIM) muS[t] = means[k*DDIM+t];
  __syncthreads();
  if(t<DDIM) A[t*SA+t] += GMM_EPS;
  __syncthreads();

  float hl = 0.f;
  // Ph1: C0
  if(w==0) hl += chol_inv32(&A[0], &W[0], l&31);
  __syncthreads();
  // Ph2: P0 (ibl=1,2,3)
  if(w==1)      panel_unit(A,W,r0,c0,0,1);
  else if(w==2) panel_unit(A,W,r0,c0,0,2);
  else if(w==3) panel_unit(A,W,r0,c0,0,3);
  __syncthreads();
  // Ph3: S0 diag (1,1) + S0 rest starts
  if(w==0)      syrk_unit(A,r0,c0,0,1,1);
  else if(w==1) syrk_unit(A,r0,c0,0,2,1);
  else if(w==2) syrk_unit(A,r0,c0,0,3,1);
  else          syrk_unit(A,r0,c0,0,2,2);
  __syncthreads();
  // Ph4: C1 || S0 rest
  if(w==0)      hl += chol_inv32(&A[32*SA+32], &W[32*SA+32], l&31);
  else if(w==1) syrk_unit(A,r0,c0,0,3,2);
  else if(w==2) syrk_unit(A,r0,c0,0,3,3);
  __syncthreads();
  // Ph5: P1 (ibl=2,3) + T_10
  if(w==1)      panel_unit(A,W,r0,c0,1,2);
  else if(w==2) panel_unit(A,W,r0,c0,1,3);
  else if(w==3) tg_unit(A,W,&Tb[0],r0,c0,1,0);
  __syncthreads();
  // Ph6: S1 diag (2,2) + A2_10 + T_21 + S1(3,2)
  if(w==0)      syrk_unit(A,r0,c0,1,2,2);
  else if(w==1) a2_unit(W,&Tb[0],r0,c0,1,0);
  else if(w==2) tg_unit(A,W,&Tb[1056],r0,c0,2,1);
  else          syrk_unit(A,r0,c0,1,3,2);
  __syncthreads();
  // Ph7: C2 || S1(3,3) + T_20 (K=64)
  if(w==0)      hl += chol_inv32(&A[64*SA+64], &W[64*SA+64], l&31);
  else if(w==1) syrk_unit(A,r0,c0,1,3,3);
  else if(w==2) tg_unit(A,W,&Tb[0],r0,c0,2,0);
  __syncthreads();
  // Ph8: P2 (ibl=3) + A2_20 + A2_21
  if(w==1)      panel_unit(A,W,r0,c0,2,3);
  else if(w==2) a2_unit(W,&Tb[0],r0,c0,2,0);
  else if(w==3) a2_unit(W,&Tb[1056],r0,c0,2,1);
  __syncthreads();
  // Ph9: S2 diag (3,3) + T_30 (K=96) + T_31 (K=64) + T_32 (K=32)
  if(w==0)      syrk_unit(A,r0,c0,2,3,3);
  else if(w==1) tg_unit(A,W,&Tb[0],r0,c0,3,0);
  else if(w==2) tg_unit(A,W,&Tb[1056],r0,c0,3,1);
  else          tg_unit(A,W,&Tb[2112],r0,c0,3,2);
  __syncthreads();
  // Ph10: C3 || m' rows 0-95 (W block-rows 0-2 final since Ph8)
  if(w==0)      hl += chol_inv32(&A[96*SA+96], &W[96*SA+96], l&31);
  else if(w==1 || (w==2 && l<32)){
    int r = (w==1)? l : 64+l;
    float s=0.f;
    #pragma unroll 8
    for(int c=0;c<DDIM;c++) s += W[r*SA+c]*muS[c];
    mq[r]=s;
  }
  __syncthreads();
  // Ph11: A2_30 + A2_31 + A2_32
  if(w==1)      a2_unit(W,&Tb[0],r0,c0,3,0);
  else if(w==2) a2_unit(W,&Tb[1056],r0,c0,3,1);
  else if(w==3) a2_unit(W,&Tb[2112],r0,c0,3,2);
  __syncthreads();
  // Ph12: m' rows 96-127 (w0) + pack U tiles 0-11 (db 0-2, final since Ph8)
  if(w==0){
    if(l<32){
      int r = 96+l;
      float s=0.f;
      #pragma unroll 8
      for(int c=0;c<DDIM;c++) s += W[r*SA+c]*muS[c];
      mq[r]=s;
    }
  } else {
    #pragma unroll
    for(int j=0;j<4;j++) pack_tile(W, ufK, (w-1)*4+j, l);
  }
  __syncthreads();
  // Ph13: q = U^T m' (t<128) + pack U tiles 12-19 (db 3, final since Ph11)
  if(t<128){
    float s=0.f;
    #pragma unroll 8
    for(int r=0;r<DDIM;r++) s += W[r*SA+t]*mq[r];
    mq[128+t]=s;
  } else if(w==2){
    #pragma unroll
    for(int j=0;j<4;j++) pack_tile(W, ufK, 12+j, l);
  } else {
    #pragma unroll
    for(int j=0;j<4;j++) pack_tile(W, ufK, 16+j, l);
  }
  __syncthreads();
  // Ph14: c3 (w0: ||m'||^2 + logdet lane-reduce) + qfrag (w1)
  if(w==0){
    float hv = (l<32)? hl : 0.f;          // lanes 32-63 hold duplicate chol
    float p  = mq[l]*mq[l] + mq[l+64]*mq[l+64];
    #pragma unroll
    for(int off=32; off; off>>=1){ hv += __shfl_xor(hv,off); p += __shfl_xor(p,off); }
    if(l==0) ws_c3[k] = logf(wts[k]) - hv - 117.6241322f - 0.5f*p;
  } else if(w==1 && l<16){
    int tile=l>>1, half=l&1;
    const float* qq=&mq[128 + tile*16 + half*8];
    unsigned uu[4];
    #pragma unroll
    for(int h2=0;h2<4;h2++){
      unsigned lo=f2bf(qq[2*h2]), hi=f2bf(qq[2*h2+1]);
      uu[h2]=lo|(hi<<16);
    }
    uint4 wv; wv.x=uu[0]; wv.y=uu[1]; wv.z=uu[2]; wv.w=uu[3];
    ((uint4*)qfrag)[tile*64 + half*32 + k] = wv;
  }
}

// ---------------------------------------------------------------------------
// k_main: EXACT R5 version (barrier-free comp loop, ~63 us). 512 thr = 8
// waves; 128 points/block staged once in LDS; wave w sweeps 4 comps with all
// 20 triangular U tiles register-resident; single logsumexp epilogue.
// ---------------------------------------------------------------------------
#define MFMA_B(acc,u,xv) acc=__builtin_amdgcn_mfma_f32_32x32x16_bf16(__builtin_bit_cast(bf16x8,u),xv,acc,0,0,0)

__global__ __launch_bounds__(512,2) void k_main(const float* __restrict__ x,
                                                const uint4* __restrict__ uf,
                                                const uint4* __restrict__ qf,
                                                const float* __restrict__ ws_c3,
                                                float* __restrict__ out){
  __shared__ uint4 xs[4*8*64];       // 32 KB: x bf16 frags [tile][c][lane]
  __shared__ float lin[KCOMP*128];   // 16 KB: -2 q.x [comp][pt]
  __shared__ float mahaS[4*8*128];   // 16 KB: ||Ux||^2 [iter][wave][pt]
  __shared__ float c3s[KCOMP];
  const int t=threadIdx.x, lane=t&63, w=t>>6;
  const int qh=lane>>5, ln=lane&31;
  const size_t n0=(size_t)blockIdx.x*128;

  if(t<KCOMP) c3s[t]=ws_c3[t];

  {
    const float* xb = x + n0*DDIM;
    #pragma unroll
    for(int j=0;j<8;j++){
      int idx = j*512 + t;
      int n = idx & 127, d0 = (idx>>7)*4;
      float4 f = *(const float4*)(xb + (size_t)n*DDIM + d0);
      unsigned lo = f2bf(f.x) | (((unsigned)f2bf(f.y))<<16);
      unsigned hi = f2bf(f.z) | (((unsigned)f2bf(f.w))<<16);
      int tile=n>>5, lnn=n&31, c=d0>>4, qq=(d0>>3)&1, e4=d0&7;
      *(uint2*)((char*)xs + tile*8192 + c*1024 + qq*512 + lnn*16 + e4*2)
          = make_uint2(lo,hi);
    }
  }
  __syncthreads();

  if(w<4){
    f32x16 aq={};
    #pragma unroll
    for(int c=0;c<8;c++){
      uint4 qr = qf[c*64+lane];
      bf16x8 xq = __builtin_bit_cast(bf16x8, xs[w*512 + c*64 + lane]);
      MFMA_B(aq, qr, xq);
    }
    #pragma unroll
    for(int r=0;r<16;r++){
      int row=(r&3)+8*(r>>2)+4*qh;
      lin[row*128 + w*32 + ln] = -2.f*aq[r];
    }
  }

  #pragma unroll 1
  for(int iter=0;iter<4;iter++){
    const int k = iter*8 + w;
    uint4 ur[20];
    #pragma unroll
    for(int j=0;j<20;j++) ur[j]=uf[(size_t)k*UFT + j*64 + lane];

    #pragma unroll 1
    for(int tile=0;tile<4;tile++){
      bf16x8 xf[8];
      #pragma unroll
      for(int c=0;c<8;c++) xf[c]=__builtin_bit_cast(bf16x8, xs[tile*512 + c*64 + lane]);
      f32x16 a0={},a1={},a2={},a3={};
      #pragma unroll
      for(int c=0;c<2;c++) MFMA_B(a0, ur[c],    xf[c]);
      #pragma unroll
      for(int c=0;c<4;c++) MFMA_B(a1, ur[2+c],  xf[c]);
      #pragma unroll
      for(int c=0;c<6;c++) MFMA_B(a2, ur[6+c],  xf[c]);
      #pragma unroll
      for(int c=0;c<8;c++) MFMA_B(a3, ur[12+c], xf[c]);
      float p0=0.f,p1=0.f,p2=0.f,p3=0.f;
      #pragma unroll
      for(int r=0;r<16;r+=2){
        p0=fmaf(a0[r],a0[r],p0); p1=fmaf(a0[r+1],a0[r+1],p1);
        p2=fmaf(a1[r],a1[r],p2); p3=fmaf(a1[r+1],a1[r+1],p3);
        p0=fmaf(a2[r],a2[r],p0); p1=fmaf(a2[r+1],a2[r+1],p1);
        p2=fmaf(a3[r],a3[r],p2); p3=fmaf(a3[r+1],a3[r+1],p3);
      }
      float p=(p0+p1)+(p2+p3);
      p += __shfl_xor(p,32);
      if(qh==0) mahaS[iter*1024 + w*128 + tile*32 + ln] = p;
    }
  }
  __syncthreads();

  if(t<128){
    float m_run=-INFINITY, s_run=0.f;
    #pragma unroll 1
    for(int k3=0;k3<KCOMP;k3++){
      float a  = c3s[k3] - 0.5f*(mahaS[(k3>>3)*1024 + (k3&7)*128 + t] + lin[k3*128 + t]);
      float nm = fmaxf(m_run,a);
      s_run = s_run*__expf(m_run-nm)+__expf(a-nm);
      m_run = nm;
    }
    out[n0+t] = m_run + logf(s_run);
  }
}

// ---------------------------------------------------------------------------
extern "C" void kernel_launch(void* const* d_in, const int* in_sizes, int n_in,
                              void* d_out, int out_size, void* d_ws, size_t ws_size,
                              hipStream_t stream){
  const float* x   = (const float*)d_in[0];
  const float* mu  = (const float*)d_in[1];
  const float* cov = (const float*)d_in[2];
  const float* wts = (const float*)d_in[3];
  float* out = (float*)d_out;
  char*  ws  = (char*)d_ws;

  float*          wsC3 = (float*)ws;                    // 128 B (c3)
  unsigned short* wsQF = (unsigned short*)(ws + 512);   // 8 KB (Q bf16 frags)
  unsigned short* wsUF = (unsigned short*)(ws + 16384); // 640 KB (U bf16 frags, tight)

  k_prep<<<KCOMP, 256, 0, stream>>>(cov, wts, mu, wsC3, wsQF, wsUF);
  k_main<<<NPTS/128, 512, 0, stream>>>(x, (const uint4*)wsUF, (const uint4*)wsQF, wsC3, out);
}